// Round 5
// baseline (802.073 us; speedup 1.0000x reference)
//
#include <hip/hip_runtime.h>

#define NN 100000
#define NE 3200000
#define HD 64

// two-phase CSR build
#define NBUCK 256
#define BWID 392                                    // 256*392 = 100352 >= NN
#define SLACK 13568                                 // avg 12544 + ~9 sigma, mult of 8
#define CAP 12                                      // staged pairs per bucket
#define P1_EPB 8192                                 // edges per partition block
#define P1_GRID ((NE + P1_EPB - 1) / P1_EPB)        // 391

typedef int   v4i __attribute__((ext_vector_type(4)));
typedef int   v2i __attribute__((ext_vector_type(2)));

__device__ __forceinline__ void fma4(float4& a, float s, const float4& b) {
    a.x = fmaf(s, b.x, a.x); a.y = fmaf(s, b.y, a.y);
    a.z = fmaf(s, b.z, a.z); a.w = fmaf(s, b.w, a.w);
}
__device__ __forceinline__ void add4(float4& a, const float4& b) {
    a.x += b.x; a.y += b.y; a.z += b.z; a.w += b.w;
}

// ---------------- phase 1: bucket partition with LDS run-staging ----------------
// Pairs are staged in LDS per bucket; every 1024 edges each bucket flushes a
// FULL 8-pair (64 B = one cache line) run written by ONE thread in 4
// consecutive dwordx4 stores -> the line closes immediately, no open-line
// working set, no partial-line writeback amplification. Reservation via
// atomicAdd(&bcur[b],8) keeps runs line-aligned. Overflow (stage full) and
// final tails fall back to direct scattered writes (rare / ~11%).
__global__ void __launch_bounds__(256) partition_kernel(
    const int* __restrict__ src, const int* __restrict__ dst,
    int* __restrict__ bcur, v2i* __restrict__ pairs) {
    __shared__ v2i stage[NBUCK][CAP];
    __shared__ int cnt[NBUCK];
    int t = threadIdx.x;
    cnt[t] = 0;                         // NBUCK == blockDim == 256
    __syncthreads();
    const v4i* d4p = (const v4i*)dst;
    const v4i* s4p = (const v4i*)src;
    const int NE4 = NE / 4;
    int base4 = blockIdx.x * (P1_EPB / 4);
    for (int it = 0; it < P1_EPB / 1024; it++) {
        int i = base4 + it * 256 + t;
        v4i d4 = (v4i){-1, -1, -1, -1};
        v4i s4 = (v4i){0, 0, 0, 0};
        if (i < NE4) {
            d4 = __builtin_nontemporal_load(d4p + i);
            s4 = __builtin_nontemporal_load(s4p + i);
        }
        #pragma unroll
        for (int k = 0; k < 4; k++) {
            int d = d4[k];
            if (d >= 0) {
                int b = (unsigned)d / BWID;
                int slot = atomicAdd(&cnt[b], 1);
                v2i p; p[0] = s4[k]; p[1] = d;
                if (slot < CAP) {
                    stage[b][slot] = p;
                } else {                 // rare overflow: direct write
                    int o = atomicAdd(&bcur[b], 1);
                    if (o < SLACK) pairs[(size_t)b * SLACK + o] = p;
                }
            }
        }
        __syncthreads();
        // drain bucket t: flush one full 64B run if available
        {
            int c = cnt[t]; if (c > CAP) c = CAP;
            if (c >= 8) {
                int gb = atomicAdd(&bcur[t], 8);
                if (gb + 8 <= SLACK) {
                    v4i* gp = (v4i*)(pairs + (size_t)t * SLACK + gb);
                    const v4i* sp = (const v4i*)&stage[t][0];
                    #pragma unroll
                    for (int m = 0; m < 4; m++) gp[m] = sp[m];
                }
                int r = c - 8;
                for (int m = 0; m < r; m++) stage[t][m] = stage[t][8 + m];
                cnt[t] = r;
            } else {
                cnt[t] = c;
            }
        }
        __syncthreads();
    }
    // final tail flush (partial runs, ~11% of edges)
    {
        int c = cnt[t]; if (c > CAP) c = CAP;
        if (c > 0) {
            int gb = atomicAdd(&bcur[t], c);
            for (int m = 0; m < c; m++)
                if (gb + m < SLACK) pairs[(size_t)t * SLACK + gb + m] = stage[t][m];
        }
    }
}

// ---------------- tiny scan over bucket counts ----------------
__global__ void bucket_scan_kernel(const int* __restrict__ bcur,
                                   int* __restrict__ bbase, int* __restrict__ rowptr) {
    __shared__ int s[NBUCK];
    int t = threadIdx.x;
    int v = bcur[t];
    s[t] = v; __syncthreads();
    for (int off = 1; off < NBUCK; off <<= 1) {
        int x = (t >= off) ? s[t - off] : 0;
        __syncthreads();
        s[t] += x;
        __syncthreads();
    }
    bbase[t] = s[t] - v;                 // exclusive prefix
    if (t == NBUCK - 1) rowptr[NN] = s[t];   // == NE
}

// ---------------- phase 2: per-bucket hist + scan + LDS scatter ----------------
// One block per bucket. Computes local degree histogram, local exclusive scan
// (-> rowptr slice + dinv slice), scatters the bucket's col slice in LDS,
// streams it out contiguously. Replaces deg/dinv/scan kernels entirely.
__global__ void __launch_bounds__(256) csr_fill_kernel(
    const v2i* __restrict__ pairs, const int* __restrict__ bcnt,
    const int* __restrict__ bbase, int* __restrict__ rowptr,
    float* __restrict__ dinv, int* __restrict__ col) {
    __shared__ int hist[BWID];
    __shared__ int rp[BWID];
    __shared__ int cur[BWID];
    __shared__ int sc[256];
    __shared__ int cols[SLACK];
    int b = blockIdx.x, t = threadIdx.x;
    int lo = b * BWID;
    int hi = min(lo + BWID, NN);
    int nw = hi - lo;
    for (int i = t; i < BWID; i += 256) { hist[i] = 0; cur[i] = 0; }
    __syncthreads();
    int np = bcnt[b]; if (np > SLACK) np = SLACK;
    int base = bbase[b];
    const v2i* pb = pairs + (size_t)b * SLACK;
    // pass 1: histogram
    for (int i = t; i < np; i += 256) {
        v2i p = pb[i];
        atomicAdd(&hist[p[1] - lo], 1);
    }
    __syncthreads();
    // exclusive scan of hist -> rp (2 elements per thread, 256-wide scan)
    int h0 = 0, s2 = 0;
    if (2 * t < BWID) {
        h0 = hist[2 * t];
        int h1 = (2 * t + 1 < BWID) ? hist[2 * t + 1] : 0;
        s2 = h0 + h1;
    }
    sc[t] = s2; __syncthreads();
    for (int off = 1; off < 256; off <<= 1) {
        int x = (t >= off) ? sc[t - off] : 0;
        __syncthreads();
        sc[t] += x;
        __syncthreads();
    }
    if (2 * t < BWID) {
        int ex = sc[t] - s2;
        rp[2 * t] = ex;
        if (2 * t + 1 < BWID) rp[2 * t + 1] = ex + h0;
    }
    __syncthreads();
    // rowptr + dinv slices (coalesced)
    for (int i = t; i < nw; i += 256) {
        rowptr[lo + i] = base + rp[i];
        dinv[lo + i] = 1.0f / sqrtf((float)(hist[i] + 1));  // +1 self-loop
    }
    // pass 2: scatter into LDS
    for (int i = t; i < np; i += 256) {
        v2i p = pb[i];
        int li = p[1] - lo;
        int slot = atomicAdd(&cur[li], 1);
        cols[rp[li] + slot] = p[0];
    }
    __syncthreads();
    // contiguous col write
    for (int i = t; i < np; i += 256)
        col[base + i] = cols[i];
}

// ---------------- fused modality encoders + GCN layer-0 matmul ----------------
// Epilogue scales row n by dinv[n]: stores hs = h * dinv  (see gather).
__global__ void __launch_bounds__(256) encmm0_kernel(
    const float* __restrict__ xf, const float* __restrict__ xw, const float* __restrict__ xt,
    const float* __restrict__ Wf, const float* __restrict__ bf,
    const float* __restrict__ Ww, const float* __restrict__ bw,
    const float* __restrict__ Wt, const float* __restrict__ bt,
    const float* __restrict__ W0, const float* __restrict__ dinv,
    float* __restrict__ h) {
    __shared__ float xin[64][32];    // fire[0..7], wea[8..19], ter[20..29]
    __shared__ float xs[64][100];    // encoder outputs for current 96-half (+4 pad)
    __shared__ float ws[96][64];     // W0 rows for current half
    int t = threadIdx.x;
    int n0 = blockIdx.x * 64;

    {
        const float4* xf4 = (const float4*)xf;
        for (int i = t; i < 128; i += 256) {
            int n = i >> 1, q = i & 1;
            int gn = n0 + n;
            float4 v = make_float4(0, 0, 0, 0);
            if (gn < NN) v = xf4[(size_t)gn * 2 + q];
            *(float4*)&xin[n][q * 4] = v;
        }
        const float4* xw4 = (const float4*)xw;
        for (int i = t; i < 192; i += 256) {
            int n = i / 3, q = i - n * 3;
            int gn = n0 + n;
            float4 v = make_float4(0, 0, 0, 0);
            if (gn < NN) v = xw4[(size_t)gn * 3 + q];
            *(float4*)&xin[n][8 + q * 4] = v;
        }
        const float2* xt2 = (const float2*)xt;
        for (int i = t; i < 320; i += 256) {
            int n = i / 5, q = i - n * 5;
            int gn = n0 + n;
            float2 v = make_float2(0, 0);
            if (gn < NN) v = xt2[(size_t)gn * 5 + q];
            *(float2*)&xin[n][20 + q * 2] = v;
        }
    }

    int cg = t & 15, ng = t >> 4;
    int c0 = cg * 4;
    float4 acc[4];
    #pragma unroll
    for (int i = 0; i < 4; i++) acc[i] = make_float4(0, 0, 0, 0);

    for (int kh = 0; kh < 2; kh++) {
        __syncthreads();
        {
            const float4* W04 = (const float4*)W0;
            float4* ws4 = (float4*)&ws[0][0];
            for (int i = t; i < 1536; i += 256)
                ws4[i] = W04[(size_t)kh * 1536 + i];
        }
        for (int i = t; i < 6144; i += 256) {
            int n = i / 96, kk = i - n * 96;
            int col = kh * 96 + kk;
            float a;
            if (col < 64) {
                a = bf[col];
                #pragma unroll
                for (int k = 0; k < 8; k++) a = fmaf(xin[n][k], Wf[k * 64 + col], a);
            } else if (col < 128) {
                int c = col - 64;
                a = bw[c];
                #pragma unroll
                for (int k = 0; k < 12; k++) a = fmaf(xin[n][8 + k], Ww[k * 64 + c], a);
            } else {
                int c = col - 128;
                a = bt[c];
                #pragma unroll
                for (int k = 0; k < 10; k++) a = fmaf(xin[n][20 + k], Wt[k * 64 + c], a);
            }
            xs[n][kk] = fmaxf(a, 0.f);
        }
        __syncthreads();
        for (int k = 0; k < 96; k += 4) {
            float4 b0 = *(const float4*)&ws[k + 0][c0];
            float4 b1 = *(const float4*)&ws[k + 1][c0];
            float4 b2 = *(const float4*)&ws[k + 2][c0];
            float4 b3 = *(const float4*)&ws[k + 3][c0];
            #pragma unroll
            for (int i = 0; i < 4; i++) {
                float4 a = *(const float4*)&xs[ng * 4 + i][k];
                fma4(acc[i], a.x, b0); fma4(acc[i], a.y, b1);
                fma4(acc[i], a.z, b2); fma4(acc[i], a.w, b3);
            }
        }
    }
    float4* h4 = (float4*)h;
    #pragma unroll
    for (int i = 0; i < 4; i++) {
        int gn = n0 + ng * 4 + i;
        if (gn < NN) {
            float dn = dinv[gn];
            float4 v = acc[i];
            v.x *= dn; v.y *= dn; v.z *= dn; v.w *= dn;
            h4[(size_t)gn * 16 + cg] = v;
        }
    }
}

// ---------------- 64x64 matmul, register-blocked: h = (x @ W) * dinv[n] ----
__global__ void __launch_bounds__(256) mm64_kernel(
    const float* __restrict__ x, const float* __restrict__ W,
    const float* __restrict__ dinv, float* __restrict__ h) {
    __shared__ float xs[64][68];
    __shared__ float ws[64][64];
    int t = threadIdx.x;
    int n0 = blockIdx.x * 64;
    {
        const float4* W4 = (const float4*)W;
        float4* ws4 = (float4*)&ws[0][0];
        for (int i = t; i < 1024; i += 256) ws4[i] = W4[i];
        const float4* x4 = (const float4*)x;
        for (int i = t; i < 1024; i += 256) {
            int n = i >> 4, q = i & 15;
            int gn = n0 + n;
            float4 v = make_float4(0, 0, 0, 0);
            if (gn < NN) v = x4[(size_t)gn * 16 + q];
            *(float4*)&xs[n][q * 4] = v;
        }
    }
    __syncthreads();
    int cg = t & 15, ng = t >> 4;
    int c0 = cg * 4;
    float4 acc[4];
    #pragma unroll
    for (int i = 0; i < 4; i++) acc[i] = make_float4(0, 0, 0, 0);
    for (int k = 0; k < 64; k += 4) {
        float4 b0 = *(const float4*)&ws[k + 0][c0];
        float4 b1 = *(const float4*)&ws[k + 1][c0];
        float4 b2 = *(const float4*)&ws[k + 2][c0];
        float4 b3 = *(const float4*)&ws[k + 3][c0];
        #pragma unroll
        for (int i = 0; i < 4; i++) {
            float4 a = *(const float4*)&xs[ng * 4 + i][k];
            fma4(acc[i], a.x, b0); fma4(acc[i], a.y, b1);
            fma4(acc[i], a.z, b2); fma4(acc[i], a.w, b3);
        }
    }
    float4* h4 = (float4*)h;
    #pragma unroll
    for (int i = 0; i < 4; i++) {
        int gn = n0 + ng * 4 + i;
        if (gn < NN) {
            float dn = dinv[gn];
            float4 v = acc[i];
            v.x *= dn; v.y *= dn; v.z *= dn; v.w *= dn;
            h4[(size_t)gn * 16 + cg] = v;
        }
    }
}

// ---------------- CSR gather + finalize ----------------
// h rows are pre-scaled by dinv (hs = h*dinv), so edges are UNWEIGHTED:
//   out[i] = relu( dinv[i] * (sum_{j->i} hs[j] + hs[i]) + b ).
// Inactive edge slots use sentinel row NN, which is kept all-zero.
__global__ void __launch_bounds__(256) gather_kernel(
    const int* __restrict__ col, const int* __restrict__ rowptr,
    const float* __restrict__ dinv, const float* __restrict__ h,
    const float* __restrict__ bias, float* __restrict__ out) {
    int n = (blockIdx.x * blockDim.x + threadIdx.x) >> 6;
    int l = threadIdx.x & 63;
    if (n >= NN) return;
    int g = l >> 4;      // edge sub-slot 0..3
    int q = l & 15;      // float4 slot 0..15
    const float4* h4 = (const float4*)h;
    float4 acc = make_float4(0, 0, 0, 0);
    int r0 = rowptr[n], r1 = rowptr[n + 1];
    for (int base = r0; base < r1; base += 64) {
        int cnt = min(64, r1 - base);
        int pv = NN;                          // sentinel: zero row
        if (l < cnt) pv = __builtin_nontemporal_load(col + base + l);
        int steps = (cnt + 3) >> 2;
        int j = 0;
        for (; j + 4 <= steps; j += 4) {
            int e0 = (j + 0) * 4 + g, e1 = (j + 1) * 4 + g;
            int e2 = (j + 2) * 4 + g, e3 = (j + 3) * 4 + g;
            int s0 = __shfl(pv, e0);
            int s1 = __shfl(pv, e1);
            int s2 = __shfl(pv, e2);
            int s3 = __shfl(pv, e3);
            float4 v0 = h4[(size_t)s0 * 16 + q];
            float4 v1 = h4[(size_t)s1 * 16 + q];
            float4 v2 = h4[(size_t)s2 * 16 + q];
            float4 v3 = h4[(size_t)s3 * 16 + q];
            add4(acc, v0); add4(acc, v1);
            add4(acc, v2); add4(acc, v3);
        }
        for (; j < steps; j++) {
            int e = j * 4 + g;
            int s = __shfl(pv, e);
            float4 v = h4[(size_t)s * 16 + q];
            add4(acc, v);
        }
    }
    acc.x += __shfl_xor(acc.x, 16); acc.y += __shfl_xor(acc.y, 16);
    acc.z += __shfl_xor(acc.z, 16); acc.w += __shfl_xor(acc.w, 16);
    acc.x += __shfl_xor(acc.x, 32); acc.y += __shfl_xor(acc.y, 32);
    acc.z += __shfl_xor(acc.z, 32); acc.w += __shfl_xor(acc.w, 32);
    if (g == 0) {
        float dn = dinv[n];
        float4 hn = h4[(size_t)n * 16 + q];   // hs[n] = h[n]*dinv[n]
        float4 b4 = ((const float4*)bias)[q];
        float4 r;
        r.x = fmaxf(fmaf(dn, acc.x + hn.x, b4.x), 0.f);
        r.y = fmaxf(fmaf(dn, acc.y + hn.y, b4.y), 0.f);
        r.z = fmaxf(fmaf(dn, acc.z + hn.z, b4.z), 0.f);
        r.w = fmaxf(fmaf(dn, acc.w + hn.w, b4.w), 0.f);
        ((float4*)out)[(size_t)n * 16 + q] = r;
    }
}

// ---------------- fused output MLP ----------------
__global__ void __launch_bounds__(256) mlp_kernel(
    const float* __restrict__ x, const float* __restrict__ w1, const float* __restrict__ b1,
    const float* __restrict__ w2, const float* __restrict__ b2, float* __restrict__ out) {
    int t = threadIdx.x;
    int nl = t >> 5, j = t & 31;
    int n = blockIdx.x * 8 + nl;
    float acc = b1[j];
    if (n < NN) {
        #pragma unroll
        for (int k = 0; k < 64; k++) acc = fmaf(x[n * 64 + k], w1[k * 32 + j], acc);
    }
    float hj = fmaxf(acc, 0.f) * w2[j];
    #pragma unroll
    for (int off = 16; off; off >>= 1) hj += __shfl_down(hj, off, 32);
    if (j == 0 && n < NN) out[n] = hj + b2[0];
}

extern "C" void kernel_launch(void* const* d_in, const int* in_sizes, int n_in,
                              void* d_out, int out_size, void* d_ws, size_t ws_size,
                              hipStream_t stream) {
    const float* xf = (const float*)d_in[0];
    const float* xw = (const float*)d_in[1];
    const float* xt = (const float*)d_in[2];
    const int*   ei = (const int*)d_in[3];
    const int*   src = ei;
    const int*   dst = ei + NE;
    const float* Wf = (const float*)d_in[4];
    const float* bf = (const float*)d_in[5];
    const float* Ww = (const float*)d_in[6];
    const float* bw = (const float*)d_in[7];
    const float* Wt = (const float*)d_in[8];
    const float* bt = (const float*)d_in[9];
    const float* W0 = (const float*)d_in[10];
    const float* b0 = (const float*)d_in[11];
    const float* W1 = (const float*)d_in[12];
    const float* b1 = (const float*)d_in[13];
    const float* W2 = (const float*)d_in[14];
    const float* b2 = (const float*)d_in[15];
    const float* ow1 = (const float*)d_in[16];
    const float* ob1 = (const float*)d_in[17];
    const float* ow2 = (const float*)d_in[18];
    const float* ob2 = (const float*)d_in[19];
    float* out = (float*)d_out;

    // workspace layout (~93 MB)
    char* w = (char*)d_ws;
    float* h      = (float*)w;  w += (size_t)(NN + 1) * 64 * 4;      // 25.6 MB (+zero row)
    float* agg    = (float*)w;  w += (size_t)NN * 64 * 4;            // 25.6 MB
    int*   col    = (int*)w;    w += (size_t)NE * 4;                 // 12.8 MB
    v2i*   pairs  = (v2i*)w;    w += (size_t)NBUCK * SLACK * 8;      // 27.8 MB
    float* dinv   = (float*)w;  w += (size_t)NN * 4;
    int*   rowptr = (int*)w;    w += (size_t)(NN + 1) * 4;
    int*   bcur   = (int*)w;    w += (size_t)NBUCK * 4;
    int*   bbase  = (int*)w;    w += (size_t)NBUCK * 4;

    // ---- CSR build (two-phase, run-staged; reused by all 3 layers) ----
    hipMemsetAsync(bcur, 0, (size_t)NBUCK * 4, stream);
    hipMemsetAsync(h + (size_t)NN * 64, 0, 64 * 4, stream);   // sentinel zero row
    partition_kernel<<<P1_GRID, 256, 0, stream>>>(src, dst, bcur, pairs);
    bucket_scan_kernel<<<1, NBUCK, 0, stream>>>(bcur, bbase, rowptr);
    csr_fill_kernel<<<NBUCK, 256, 0, stream>>>(pairs, bcur, bbase, rowptr, dinv, col);

    // ---- layer 0: fused encoders + matmul (scaled), then gather+finalize ----
    encmm0_kernel<<<(NN + 63) / 64, 256, 0, stream>>>(xf, xw, xt, Wf, bf, Ww, bw, Wt, bt, W0, dinv, h);
    gather_kernel<<<(NN * 64 + 255) / 256, 256, 0, stream>>>(col, rowptr, dinv, h, b0, agg);

    // ---- layer 1 ----
    mm64_kernel<<<(NN + 63) / 64, 256, 0, stream>>>(agg, W1, dinv, h);
    gather_kernel<<<(NN * 64 + 255) / 256, 256, 0, stream>>>(col, rowptr, dinv, h, b1, agg);

    // ---- layer 2 ----
    mm64_kernel<<<(NN + 63) / 64, 256, 0, stream>>>(agg, W2, dinv, h);
    gather_kernel<<<(NN * 64 + 255) / 256, 256, 0, stream>>>(col, rowptr, dinv, h, b2, agg);

    // ---- output MLP ----
    mlp_kernel<<<(NN + 7) / 8, 256, 0, stream>>>(agg, ow1, ob1, ow2, ob2, out);
}

// Round 6
// 729.702 us; speedup vs baseline: 1.0992x; 1.0992x over previous
//
#include <hip/hip_runtime.h>

#define NN 100000
#define NE 3200000
#define HD 64

// two-phase CSR build
#define NBUCK 256
#define BWID 392                                    // 256*392 = 100352 >= NN
#define SLACK 20480                                 // slots/bucket: 12544 real + ~5500 pad + margin
#define COLCAP 13568                                // real cols/bucket cap (12544 + ~9 sigma)
#define OVFCAP 512                                  // overflow pairs/bucket
#define CAP 16                                      // staged pairs per bucket per block
#define P1_EPB 2048                                 // edges per partition block
#define P1_GRID ((NE + P1_EPB - 1) / P1_EPB)        // 1563

typedef int   v4i __attribute__((ext_vector_type(4)));
typedef int   v2i __attribute__((ext_vector_type(2)));

__device__ __forceinline__ void fma4(float4& a, float s, const float4& b) {
    a.x = fmaf(s, b.x, a.x); a.y = fmaf(s, b.y, a.y);
    a.z = fmaf(s, b.z, a.z); a.w = fmaf(s, b.w, a.w);
}
__device__ __forceinline__ void add4(float4& a, const float4& b) {
    a.x += b.x; a.y += b.y; a.z += b.z; a.w += b.w;
}

// ---------------- phase 1: bucket partition, LDS-staged, 1 drain/block ----------------
// 1563 blocks x 2048 edges. All edges staged in LDS per bucket (avg 8, CAP 16),
// ONE drain at block end: each bucket flushes ceil(c/8)*8 slots (full 64B lines,
// sentinel d=-1 pads) reserved via one padded-line atomic -> every pairs line is
// written completely, once, by one thread's 4 consecutive dwordx4 stores.
// bctl[b*16+0]=slot cursor, +1=real count, +2=overflow cursor (each bucket owns
// a full 64B line -> no cross-bucket atomic line contention).
__global__ void __launch_bounds__(256) partition_kernel(
    const int* __restrict__ src, const int* __restrict__ dst,
    int* __restrict__ bctl, v2i* __restrict__ pairs, v2i* __restrict__ povf) {
    __shared__ v2i stage[NBUCK][CAP];
    __shared__ int cnt[NBUCK];
    int t = threadIdx.x;
    cnt[t] = 0;                         // NBUCK == blockDim == 256
    __syncthreads();
    const v4i* d4p = (const v4i*)dst;
    const v4i* s4p = (const v4i*)src;
    const int NE4 = NE / 4;
    int base4 = blockIdx.x * (P1_EPB / 4);
    #pragma unroll
    for (int it = 0; it < P1_EPB / 1024; it++) {
        int i = base4 + it * 256 + t;
        v4i d4 = (v4i){-1, -1, -1, -1};
        v4i s4 = (v4i){0, 0, 0, 0};
        if (i < NE4) {
            d4 = __builtin_nontemporal_load(d4p + i);
            s4 = __builtin_nontemporal_load(s4p + i);
        }
        #pragma unroll
        for (int k = 0; k < 4; k++) {
            int d = d4[k];
            if (d >= 0) {
                int b = (unsigned)d / BWID;
                int slot = atomicAdd(&cnt[b], 1);
                v2i p; p[0] = s4[k]; p[1] = d;
                if (slot < CAP) {
                    stage[b][slot] = p;
                } else {                 // rare overflow -> separate region
                    int o = atomicAdd(&bctl[b * 16 + 2], 1);
                    if (o < OVFCAP) povf[(size_t)b * OVFCAP + o] = p;
                }
            }
        }
    }
    __syncthreads();
    // drain bucket t (single drain per block)
    int c_tot = cnt[t];
    int c = (c_tot > CAP) ? CAP : c_tot;
    int runs = (c + 7) >> 3;             // 0..2
    if (runs) {
        int slots = runs * 8;            // 8 or 16, <= CAP
        for (int m = c; m < slots; m++) { v2i p; p[0] = 0; p[1] = -1; stage[t][m] = p; }
        int gb = atomicAdd(&bctl[t * 16], slots);   // stays multiple of 8
        if (gb + slots <= SLACK) {
            v4i* gp = (v4i*)(pairs + (size_t)t * SLACK + gb);
            const v4i* sp = (const v4i*)&stage[t][0];
            #pragma unroll
            for (int m = 0; m < 8; m++) { if (m < runs * 4) gp[m] = sp[m]; }
        } else {
            for (int m = 0; m < slots && gb + m < SLACK; m++)
                pairs[(size_t)t * SLACK + gb + m] = stage[t][m];
        }
    }
    if (c_tot > 0) atomicAdd(&bctl[t * 16 + 1], c_tot);   // real contribution
}

// ---------------- tiny scan over real bucket counts ----------------
__global__ void bucket_scan_kernel(const int* __restrict__ bctl,
                                   int* __restrict__ bbase, int* __restrict__ rowptr) {
    __shared__ int s[NBUCK];
    int t = threadIdx.x;
    int v = bctl[t * 16 + 1];
    s[t] = v; __syncthreads();
    for (int off = 1; off < NBUCK; off <<= 1) {
        int x = (t >= off) ? s[t - off] : 0;
        __syncthreads();
        s[t] += x;
        __syncthreads();
    }
    bbase[t] = s[t] - v;                 // exclusive prefix of real counts
    if (t == NBUCK - 1) rowptr[NN] = s[t];   // == NE
}

// ---------------- phase 2: per-bucket hist + scan + LDS scatter ----------------
// One block per bucket. Skips sentinel (d=-1) pad slots; also consumes the
// bucket's overflow region. Emits rowptr slice, dinv slice, contiguous col.
__global__ void __launch_bounds__(256) csr_fill_kernel(
    const v2i* __restrict__ pairs, const v2i* __restrict__ povf,
    const int* __restrict__ bctl, const int* __restrict__ bbase,
    int* __restrict__ rowptr, float* __restrict__ dinv, int* __restrict__ col) {
    __shared__ int hist[BWID];
    __shared__ int rp[BWID];
    __shared__ int cur[BWID];
    __shared__ int sc[256];
    __shared__ int cols[COLCAP];
    int b = blockIdx.x, t = threadIdx.x;
    int lo = b * BWID;
    int hi = min(lo + BWID, NN);
    int nw = hi - lo;
    for (int i = t; i < BWID; i += 256) { hist[i] = 0; cur[i] = 0; }
    __syncthreads();
    int np = bctl[b * 16];     if (np > SLACK) np = SLACK;
    int nov = bctl[b * 16 + 2]; if (nov > OVFCAP) nov = OVFCAP;
    int base = bbase[b];
    const v2i* pb = pairs + (size_t)b * SLACK;
    const v2i* ob = povf + (size_t)b * OVFCAP;
    // pass 1: histogram (skip sentinels)
    for (int i = t; i < np; i += 256) {
        v2i p = pb[i];
        if (p[1] >= 0) atomicAdd(&hist[p[1] - lo], 1);
    }
    for (int i = t; i < nov; i += 256) {
        v2i p = ob[i];
        atomicAdd(&hist[p[1] - lo], 1);
    }
    __syncthreads();
    // exclusive scan of hist -> rp (2 elements per thread)
    int h0 = 0, s2 = 0;
    if (2 * t < BWID) {
        h0 = hist[2 * t];
        int h1 = (2 * t + 1 < BWID) ? hist[2 * t + 1] : 0;
        s2 = h0 + h1;
    }
    sc[t] = s2; __syncthreads();
    for (int off = 1; off < 256; off <<= 1) {
        int x = (t >= off) ? sc[t - off] : 0;
        __syncthreads();
        sc[t] += x;
        __syncthreads();
    }
    if (2 * t < BWID) {
        int ex = sc[t] - s2;
        rp[2 * t] = ex;
        if (2 * t + 1 < BWID) rp[2 * t + 1] = ex + h0;
    }
    __syncthreads();
    // rowptr + dinv slices (coalesced)
    for (int i = t; i < nw; i += 256) {
        rowptr[lo + i] = base + rp[i];
        dinv[lo + i] = 1.0f / sqrtf((float)(hist[i] + 1));  // +1 self-loop
    }
    // pass 2: scatter into LDS
    for (int i = t; i < np; i += 256) {
        v2i p = pb[i];
        if (p[1] >= 0) {
            int li = p[1] - lo;
            int slot = atomicAdd(&cur[li], 1);
            int o = rp[li] + slot;
            if (o < COLCAP) cols[o] = p[0];
        }
    }
    for (int i = t; i < nov; i += 256) {
        v2i p = ob[i];
        int li = p[1] - lo;
        int slot = atomicAdd(&cur[li], 1);
        int o = rp[li] + slot;
        if (o < COLCAP) cols[o] = p[0];
    }
    __syncthreads();
    // contiguous col write (real count only)
    int nreal = bctl[b * 16 + 1]; if (nreal > COLCAP) nreal = COLCAP;
    for (int i = t; i < nreal; i += 256)
        col[base + i] = cols[i];
}

// ---------------- fused modality encoders + GCN layer-0 matmul ----------------
// Epilogue scales row n by dinv[n]: stores hs = h * dinv  (see gather).
__global__ void __launch_bounds__(256) encmm0_kernel(
    const float* __restrict__ xf, const float* __restrict__ xw, const float* __restrict__ xt,
    const float* __restrict__ Wf, const float* __restrict__ bf,
    const float* __restrict__ Ww, const float* __restrict__ bw,
    const float* __restrict__ Wt, const float* __restrict__ bt,
    const float* __restrict__ W0, const float* __restrict__ dinv,
    float* __restrict__ h) {
    __shared__ float xin[64][32];    // fire[0..7], wea[8..19], ter[20..29]
    __shared__ float xs[64][100];    // encoder outputs for current 96-half (+4 pad)
    __shared__ float ws[96][64];     // W0 rows for current half
    int t = threadIdx.x;
    int n0 = blockIdx.x * 64;

    {
        const float4* xf4 = (const float4*)xf;
        for (int i = t; i < 128; i += 256) {
            int n = i >> 1, q = i & 1;
            int gn = n0 + n;
            float4 v = make_float4(0, 0, 0, 0);
            if (gn < NN) v = xf4[(size_t)gn * 2 + q];
            *(float4*)&xin[n][q * 4] = v;
        }
        const float4* xw4 = (const float4*)xw;
        for (int i = t; i < 192; i += 256) {
            int n = i / 3, q = i - n * 3;
            int gn = n0 + n;
            float4 v = make_float4(0, 0, 0, 0);
            if (gn < NN) v = xw4[(size_t)gn * 3 + q];
            *(float4*)&xin[n][8 + q * 4] = v;
        }
        const float2* xt2 = (const float2*)xt;
        for (int i = t; i < 320; i += 256) {
            int n = i / 5, q = i - n * 5;
            int gn = n0 + n;
            float2 v = make_float2(0, 0);
            if (gn < NN) v = xt2[(size_t)gn * 5 + q];
            *(float2*)&xin[n][20 + q * 2] = v;
        }
    }

    int cg = t & 15, ng = t >> 4;
    int c0 = cg * 4;
    float4 acc[4];
    #pragma unroll
    for (int i = 0; i < 4; i++) acc[i] = make_float4(0, 0, 0, 0);

    for (int kh = 0; kh < 2; kh++) {
        __syncthreads();
        {
            const float4* W04 = (const float4*)W0;
            float4* ws4 = (float4*)&ws[0][0];
            for (int i = t; i < 1536; i += 256)
                ws4[i] = W04[(size_t)kh * 1536 + i];
        }
        for (int i = t; i < 6144; i += 256) {
            int n = i / 96, kk = i - n * 96;
            int col = kh * 96 + kk;
            float a;
            if (col < 64) {
                a = bf[col];
                #pragma unroll
                for (int k = 0; k < 8; k++) a = fmaf(xin[n][k], Wf[k * 64 + col], a);
            } else if (col < 128) {
                int c = col - 64;
                a = bw[c];
                #pragma unroll
                for (int k = 0; k < 12; k++) a = fmaf(xin[n][8 + k], Ww[k * 64 + c], a);
            } else {
                int c = col - 128;
                a = bt[c];
                #pragma unroll
                for (int k = 0; k < 10; k++) a = fmaf(xin[n][20 + k], Wt[k * 64 + c], a);
            }
            xs[n][kk] = fmaxf(a, 0.f);
        }
        __syncthreads();
        for (int k = 0; k < 96; k += 4) {
            float4 b0 = *(const float4*)&ws[k + 0][c0];
            float4 b1 = *(const float4*)&ws[k + 1][c0];
            float4 b2 = *(const float4*)&ws[k + 2][c0];
            float4 b3 = *(const float4*)&ws[k + 3][c0];
            #pragma unroll
            for (int i = 0; i < 4; i++) {
                float4 a = *(const float4*)&xs[ng * 4 + i][k];
                fma4(acc[i], a.x, b0); fma4(acc[i], a.y, b1);
                fma4(acc[i], a.z, b2); fma4(acc[i], a.w, b3);
            }
        }
    }
    float4* h4 = (float4*)h;
    #pragma unroll
    for (int i = 0; i < 4; i++) {
        int gn = n0 + ng * 4 + i;
        if (gn < NN) {
            float dn = dinv[gn];
            float4 v = acc[i];
            v.x *= dn; v.y *= dn; v.z *= dn; v.w *= dn;
            h4[(size_t)gn * 16 + cg] = v;
        }
    }
}

// ---------------- 64x64 matmul, register-blocked: h = (x @ W) * dinv[n] ----
__global__ void __launch_bounds__(256) mm64_kernel(
    const float* __restrict__ x, const float* __restrict__ W,
    const float* __restrict__ dinv, float* __restrict__ h) {
    __shared__ float xs[64][68];
    __shared__ float ws[64][64];
    int t = threadIdx.x;
    int n0 = blockIdx.x * 64;
    {
        const float4* W4 = (const float4*)W;
        float4* ws4 = (float4*)&ws[0][0];
        for (int i = t; i < 1024; i += 256) ws4[i] = W4[i];
        const float4* x4 = (const float4*)x;
        for (int i = t; i < 1024; i += 256) {
            int n = i >> 4, q = i & 15;
            int gn = n0 + n;
            float4 v = make_float4(0, 0, 0, 0);
            if (gn < NN) v = x4[(size_t)gn * 16 + q];
            *(float4*)&xs[n][q * 4] = v;
        }
    }
    __syncthreads();
    int cg = t & 15, ng = t >> 4;
    int c0 = cg * 4;
    float4 acc[4];
    #pragma unroll
    for (int i = 0; i < 4; i++) acc[i] = make_float4(0, 0, 0, 0);
    for (int k = 0; k < 64; k += 4) {
        float4 b0 = *(const float4*)&ws[k + 0][c0];
        float4 b1 = *(const float4*)&ws[k + 1][c0];
        float4 b2 = *(const float4*)&ws[k + 2][c0];
        float4 b3 = *(const float4*)&ws[k + 3][c0];
        #pragma unroll
        for (int i = 0; i < 4; i++) {
            float4 a = *(const float4*)&xs[ng * 4 + i][k];
            fma4(acc[i], a.x, b0); fma4(acc[i], a.y, b1);
            fma4(acc[i], a.z, b2); fma4(acc[i], a.w, b3);
        }
    }
    float4* h4 = (float4*)h;
    #pragma unroll
    for (int i = 0; i < 4; i++) {
        int gn = n0 + ng * 4 + i;
        if (gn < NN) {
            float dn = dinv[gn];
            float4 v = acc[i];
            v.x *= dn; v.y *= dn; v.z *= dn; v.w *= dn;
            h4[(size_t)gn * 16 + cg] = v;
        }
    }
}

// ---------------- CSR gather + finalize ----------------
// h rows are pre-scaled by dinv (hs = h*dinv), so edges are UNWEIGHTED:
//   out[i] = relu( dinv[i] * (sum_{j->i} hs[j] + hs[i]) + b ).
// Inactive edge slots use sentinel row NN, which is kept all-zero.
__global__ void __launch_bounds__(256) gather_kernel(
    const int* __restrict__ col, const int* __restrict__ rowptr,
    const float* __restrict__ dinv, const float* __restrict__ h,
    const float* __restrict__ bias, float* __restrict__ out) {
    int n = (blockIdx.x * blockDim.x + threadIdx.x) >> 6;
    int l = threadIdx.x & 63;
    if (n >= NN) return;
    int g = l >> 4;      // edge sub-slot 0..3
    int q = l & 15;      // float4 slot 0..15
    const float4* h4 = (const float4*)h;
    float4 acc = make_float4(0, 0, 0, 0);
    int r0 = rowptr[n], r1 = rowptr[n + 1];
    for (int base = r0; base < r1; base += 64) {
        int cnt = min(64, r1 - base);
        int pv = NN;                          // sentinel: zero row
        if (l < cnt) pv = __builtin_nontemporal_load(col + base + l);
        int steps = (cnt + 3) >> 2;
        int j = 0;
        for (; j + 4 <= steps; j += 4) {
            int e0 = (j + 0) * 4 + g, e1 = (j + 1) * 4 + g;
            int e2 = (j + 2) * 4 + g, e3 = (j + 3) * 4 + g;
            int s0 = __shfl(pv, e0);
            int s1 = __shfl(pv, e1);
            int s2 = __shfl(pv, e2);
            int s3 = __shfl(pv, e3);
            float4 v0 = h4[(size_t)s0 * 16 + q];
            float4 v1 = h4[(size_t)s1 * 16 + q];
            float4 v2 = h4[(size_t)s2 * 16 + q];
            float4 v3 = h4[(size_t)s3 * 16 + q];
            add4(acc, v0); add4(acc, v1);
            add4(acc, v2); add4(acc, v3);
        }
        for (; j < steps; j++) {
            int e = j * 4 + g;
            int s = __shfl(pv, e);
            float4 v = h4[(size_t)s * 16 + q];
            add4(acc, v);
        }
    }
    acc.x += __shfl_xor(acc.x, 16); acc.y += __shfl_xor(acc.y, 16);
    acc.z += __shfl_xor(acc.z, 16); acc.w += __shfl_xor(acc.w, 16);
    acc.x += __shfl_xor(acc.x, 32); acc.y += __shfl_xor(acc.y, 32);
    acc.z += __shfl_xor(acc.z, 32); acc.w += __shfl_xor(acc.w, 32);
    if (g == 0) {
        float dn = dinv[n];
        float4 hn = h4[(size_t)n * 16 + q];   // hs[n] = h[n]*dinv[n]
        float4 b4 = ((const float4*)bias)[q];
        float4 r;
        r.x = fmaxf(fmaf(dn, acc.x + hn.x, b4.x), 0.f);
        r.y = fmaxf(fmaf(dn, acc.y + hn.y, b4.y), 0.f);
        r.z = fmaxf(fmaf(dn, acc.z + hn.z, b4.z), 0.f);
        r.w = fmaxf(fmaf(dn, acc.w + hn.w, b4.w), 0.f);
        ((float4*)out)[(size_t)n * 16 + q] = r;
    }
}

// ---------------- fused output MLP ----------------
__global__ void __launch_bounds__(256) mlp_kernel(
    const float* __restrict__ x, const float* __restrict__ w1, const float* __restrict__ b1,
    const float* __restrict__ w2, const float* __restrict__ b2, float* __restrict__ out) {
    int t = threadIdx.x;
    int nl = t >> 5, j = t & 31;
    int n = blockIdx.x * 8 + nl;
    float acc = b1[j];
    if (n < NN) {
        #pragma unroll
        for (int k = 0; k < 64; k++) acc = fmaf(x[n * 64 + k], w1[k * 32 + j], acc);
    }
    float hj = fmaxf(acc, 0.f) * w2[j];
    #pragma unroll
    for (int off = 16; off; off >>= 1) hj += __shfl_down(hj, off, 32);
    if (j == 0 && n < NN) out[n] = hj + b2[0];
}

extern "C" void kernel_launch(void* const* d_in, const int* in_sizes, int n_in,
                              void* d_out, int out_size, void* d_ws, size_t ws_size,
                              hipStream_t stream) {
    const float* xf = (const float*)d_in[0];
    const float* xw = (const float*)d_in[1];
    const float* xt = (const float*)d_in[2];
    const int*   ei = (const int*)d_in[3];
    const int*   src = ei;
    const int*   dst = ei + NE;
    const float* Wf = (const float*)d_in[4];
    const float* bf = (const float*)d_in[5];
    const float* Ww = (const float*)d_in[6];
    const float* bw = (const float*)d_in[7];
    const float* Wt = (const float*)d_in[8];
    const float* bt = (const float*)d_in[9];
    const float* W0 = (const float*)d_in[10];
    const float* b0 = (const float*)d_in[11];
    const float* W1 = (const float*)d_in[12];
    const float* b1 = (const float*)d_in[13];
    const float* W2 = (const float*)d_in[14];
    const float* b2 = (const float*)d_in[15];
    const float* ow1 = (const float*)d_in[16];
    const float* ob1 = (const float*)d_in[17];
    const float* ow2 = (const float*)d_in[18];
    const float* ob2 = (const float*)d_in[19];
    float* out = (float*)d_out;

    // workspace layout (~65 MB). pairs (42 MB) ALIASES h+agg: it is dead before
    // encmm0 writes h (stream-ordered after csr_fill reads pairs).
    char* w = (char*)d_ws;
    float* h      = (float*)w;  w += (size_t)(NN + 1) * 64 * 4;      // 25.6 MB (+zero row)
    float* agg    = (float*)w;  w += (size_t)NN * 64 * 4;            // 25.6 MB
    int*   col    = (int*)w;    w += (size_t)NE * 4;                 // 12.8 MB
    v2i*   povf   = (v2i*)w;    w += (size_t)NBUCK * OVFCAP * 8;     // 1 MB
    float* dinv   = (float*)w;  w += (size_t)NN * 4;
    int*   rowptr = (int*)w;    w += (size_t)(NN + 1) * 4;
    int*   bctl   = (int*)w;    w += (size_t)NBUCK * 16 * 4;         // 16 KB (padded lines)
    int*   bbase  = (int*)w;    w += (size_t)NBUCK * 4;
    v2i*   pairs  = (v2i*)h;                                         // alias (42 MB <= 51.2 MB)

    // ---- CSR build (two-phase, line-staged; reused by all 3 layers) ----
    hipMemsetAsync(bctl, 0, (size_t)NBUCK * 16 * 4, stream);
    partition_kernel<<<P1_GRID, 256, 0, stream>>>(src, dst, bctl, pairs, povf);
    bucket_scan_kernel<<<1, NBUCK, 0, stream>>>(bctl, bbase, rowptr);
    csr_fill_kernel<<<NBUCK, 256, 0, stream>>>(pairs, povf, bctl, bbase, rowptr, dinv, col);
    hipMemsetAsync(h + (size_t)NN * 64, 0, 64 * 4, stream);   // sentinel zero row (after pairs dead)

    // ---- layer 0: fused encoders + matmul (scaled), then gather+finalize ----
    encmm0_kernel<<<(NN + 63) / 64, 256, 0, stream>>>(xf, xw, xt, Wf, bf, Ww, bw, Wt, bt, W0, dinv, h);
    gather_kernel<<<(NN * 64 + 255) / 256, 256, 0, stream>>>(col, rowptr, dinv, h, b0, agg);

    // ---- layer 1 ----
    mm64_kernel<<<(NN + 63) / 64, 256, 0, stream>>>(agg, W1, dinv, h);
    gather_kernel<<<(NN * 64 + 255) / 256, 256, 0, stream>>>(col, rowptr, dinv, h, b1, agg);

    // ---- layer 2 ----
    mm64_kernel<<<(NN + 63) / 64, 256, 0, stream>>>(agg, W2, dinv, h);
    gather_kernel<<<(NN * 64 + 255) / 256, 256, 0, stream>>>(col, rowptr, dinv, h, b2, agg);

    // ---- output MLP ----
    mlp_kernel<<<(NN + 7) / 8, 256, 0, stream>>>(agg, ow1, ob1, ow2, ob2, out);
}

// Round 7
// 694.090 us; speedup vs baseline: 1.1556x; 1.0513x over previous
//
#include <hip/hip_runtime.h>

#define NN 100000
#define NE 3200000
#define HD 64

// two-phase CSR build
#define NBUCK 256
#define BWID 392                                    // 256*392 = 100352 >= NN
#define SLACK 20480                                 // slots/bucket: 12544 real + ~5500 pad + margin
#define COLCAP 13568                                // real cols/bucket cap (12544 + ~9 sigma)
#define OVFCAP 512                                  // overflow pairs/bucket
#define CAP 16                                      // staged pairs per bucket per block
#define P1_EPB 2048                                 // edges per partition block
#define P1_GRID ((NE + P1_EPB - 1) / P1_EPB)        // 1563

typedef int   v4i __attribute__((ext_vector_type(4)));
typedef int   v2i __attribute__((ext_vector_type(2)));

__device__ __forceinline__ void fma4(float4& a, float s, const float4& b) {
    a.x = fmaf(s, b.x, a.x); a.y = fmaf(s, b.y, a.y);
    a.z = fmaf(s, b.z, a.z); a.w = fmaf(s, b.w, a.w);
}
__device__ __forceinline__ void add4(float4& a, const float4& b) {
    a.x += b.x; a.y += b.y; a.z += b.z; a.w += b.w;
}

// ---------------- phase 1: bucket partition, LDS-staged, 1 drain/block ----------------
__global__ void __launch_bounds__(256) partition_kernel(
    const int* __restrict__ src, const int* __restrict__ dst,
    int* __restrict__ bctl, v2i* __restrict__ pairs, v2i* __restrict__ povf) {
    __shared__ v2i stage[NBUCK][CAP];
    __shared__ int cnt[NBUCK];
    int t = threadIdx.x;
    cnt[t] = 0;                         // NBUCK == blockDim == 256
    __syncthreads();
    const v4i* d4p = (const v4i*)dst;
    const v4i* s4p = (const v4i*)src;
    const int NE4 = NE / 4;
    int base4 = blockIdx.x * (P1_EPB / 4);
    #pragma unroll
    for (int it = 0; it < P1_EPB / 1024; it++) {
        int i = base4 + it * 256 + t;
        v4i d4 = (v4i){-1, -1, -1, -1};
        v4i s4 = (v4i){0, 0, 0, 0};
        if (i < NE4) {
            d4 = __builtin_nontemporal_load(d4p + i);
            s4 = __builtin_nontemporal_load(s4p + i);
        }
        #pragma unroll
        for (int k = 0; k < 4; k++) {
            int d = d4[k];
            if (d >= 0) {
                int b = (unsigned)d / BWID;
                int slot = atomicAdd(&cnt[b], 1);
                v2i p; p[0] = s4[k]; p[1] = d;
                if (slot < CAP) {
                    stage[b][slot] = p;
                } else {                 // rare overflow -> separate region
                    int o = atomicAdd(&bctl[b * 16 + 2], 1);
                    if (o < OVFCAP) povf[(size_t)b * OVFCAP + o] = p;
                }
            }
        }
    }
    __syncthreads();
    // drain bucket t (single drain per block)
    int c_tot = cnt[t];
    int c = (c_tot > CAP) ? CAP : c_tot;
    int runs = (c + 7) >> 3;             // 0..2
    if (runs) {
        int slots = runs * 8;            // 8 or 16, <= CAP
        for (int m = c; m < slots; m++) { v2i p; p[0] = 0; p[1] = -1; stage[t][m] = p; }
        int gb = atomicAdd(&bctl[t * 16], slots);   // stays multiple of 8
        if (gb + slots <= SLACK) {
            v4i* gp = (v4i*)(pairs + (size_t)t * SLACK + gb);
            const v4i* sp = (const v4i*)&stage[t][0];
            #pragma unroll
            for (int m = 0; m < 8; m++) { if (m < runs * 4) gp[m] = sp[m]; }
        } else {
            for (int m = 0; m < slots && gb + m < SLACK; m++)
                pairs[(size_t)t * SLACK + gb + m] = stage[t][m];
        }
    }
    if (c_tot > 0) atomicAdd(&bctl[t * 16 + 1], c_tot);   // real contribution
}

// ---------------- tiny scan over real bucket counts ----------------
__global__ void bucket_scan_kernel(const int* __restrict__ bctl,
                                   int* __restrict__ bbase, int* __restrict__ rowptr) {
    __shared__ int s[NBUCK];
    int t = threadIdx.x;
    int v = bctl[t * 16 + 1];
    s[t] = v; __syncthreads();
    for (int off = 1; off < NBUCK; off <<= 1) {
        int x = (t >= off) ? s[t - off] : 0;
        __syncthreads();
        s[t] += x;
        __syncthreads();
    }
    bbase[t] = s[t] - v;                 // exclusive prefix of real counts
    if (t == NBUCK - 1) rowptr[NN] = s[t];   // == NE
}

// ---------------- phase 2: per-bucket hist + scan + LDS scatter ----------------
__global__ void __launch_bounds__(256) csr_fill_kernel(
    const v2i* __restrict__ pairs, const v2i* __restrict__ povf,
    const int* __restrict__ bctl, const int* __restrict__ bbase,
    int* __restrict__ rowptr, float* __restrict__ dinv, int* __restrict__ col) {
    __shared__ int hist[BWID];
    __shared__ int rp[BWID];
    __shared__ int cur[BWID];
    __shared__ int sc[256];
    __shared__ int cols[COLCAP];
    int b = blockIdx.x, t = threadIdx.x;
    int lo = b * BWID;
    int hi = min(lo + BWID, NN);
    int nw = hi - lo;
    for (int i = t; i < BWID; i += 256) { hist[i] = 0; cur[i] = 0; }
    __syncthreads();
    int np = bctl[b * 16];     if (np > SLACK) np = SLACK;
    int nov = bctl[b * 16 + 2]; if (nov > OVFCAP) nov = OVFCAP;
    int base = bbase[b];
    const v2i* pb = pairs + (size_t)b * SLACK;
    const v2i* ob = povf + (size_t)b * OVFCAP;
    // pass 1: histogram (skip sentinels)
    for (int i = t; i < np; i += 256) {
        v2i p = pb[i];
        if (p[1] >= 0) atomicAdd(&hist[p[1] - lo], 1);
    }
    for (int i = t; i < nov; i += 256) {
        v2i p = ob[i];
        atomicAdd(&hist[p[1] - lo], 1);
    }
    __syncthreads();
    // exclusive scan of hist -> rp (2 elements per thread)
    int h0 = 0, s2 = 0;
    if (2 * t < BWID) {
        h0 = hist[2 * t];
        int h1 = (2 * t + 1 < BWID) ? hist[2 * t + 1] : 0;
        s2 = h0 + h1;
    }
    sc[t] = s2; __syncthreads();
    for (int off = 1; off < 256; off <<= 1) {
        int x = (t >= off) ? sc[t - off] : 0;
        __syncthreads();
        sc[t] += x;
        __syncthreads();
    }
    if (2 * t < BWID) {
        int ex = sc[t] - s2;
        rp[2 * t] = ex;
        if (2 * t + 1 < BWID) rp[2 * t + 1] = ex + h0;
    }
    __syncthreads();
    // rowptr + dinv slices (coalesced)
    for (int i = t; i < nw; i += 256) {
        rowptr[lo + i] = base + rp[i];
        dinv[lo + i] = 1.0f / sqrtf((float)(hist[i] + 1));  // +1 self-loop
    }
    // pass 2: scatter into LDS
    for (int i = t; i < np; i += 256) {
        v2i p = pb[i];
        if (p[1] >= 0) {
            int li = p[1] - lo;
            int slot = atomicAdd(&cur[li], 1);
            int o = rp[li] + slot;
            if (o < COLCAP) cols[o] = p[0];
        }
    }
    for (int i = t; i < nov; i += 256) {
        v2i p = ob[i];
        int li = p[1] - lo;
        int slot = atomicAdd(&cur[li], 1);
        int o = rp[li] + slot;
        if (o < COLCAP) cols[o] = p[0];
    }
    __syncthreads();
    // contiguous col write (real count only)
    int nreal = bctl[b * 16 + 1]; if (nreal > COLCAP) nreal = COLCAP;
    for (int i = t; i < nreal; i += 256)
        col[base + i] = cols[i];
}

// ---------------- fused modality encoders + GCN layer-0 matmul (v2) ----------------
// K=192 split into 6 slices of 32 (slice boundaries align with modality blocks
// -> uniform branch). Encoder weights (30x64) + biases staged in LDS once: the
// encoder inner loop is pure-LDS FMA. LDS total 34 KB -> 4 blocks/CU (2x v1).
// Epilogue scales row n by dinv[n]: stores hs = h * dinv (see gather).
__global__ void __launch_bounds__(256) encmm0_kernel(
    const float* __restrict__ xf, const float* __restrict__ xw, const float* __restrict__ xt,
    const float* __restrict__ Wf, const float* __restrict__ bf,
    const float* __restrict__ Ww, const float* __restrict__ bw,
    const float* __restrict__ Wt, const float* __restrict__ bt,
    const float* __restrict__ W0, const float* __restrict__ dinv,
    float* __restrict__ h) {
    __shared__ float xin[64][32];    // fire[0..7], wea[8..19], ter[20..29]
    __shared__ float wenc[30][64];   // encoder weights (rows match xin cols)
    __shared__ float bs[192];        // encoder biases
    __shared__ float xs[64][36];     // encoder outputs for current 32-slice (+4 pad)
    __shared__ float ws[32][64];     // W0 rows for current slice
    int t = threadIdx.x;
    int n0 = blockIdx.x * 64;

    {   // stage raw inputs
        const float4* xf4 = (const float4*)xf;
        for (int i = t; i < 128; i += 256) {
            int n = i >> 1, q = i & 1;
            int gn = n0 + n;
            float4 v = make_float4(0, 0, 0, 0);
            if (gn < NN) v = xf4[(size_t)gn * 2 + q];
            *(float4*)&xin[n][q * 4] = v;
        }
        const float4* xw4 = (const float4*)xw;
        for (int i = t; i < 192; i += 256) {
            int n = i / 3, q = i - n * 3;
            int gn = n0 + n;
            float4 v = make_float4(0, 0, 0, 0);
            if (gn < NN) v = xw4[(size_t)gn * 3 + q];
            *(float4*)&xin[n][8 + q * 4] = v;
        }
        const float2* xt2 = (const float2*)xt;
        for (int i = t; i < 320; i += 256) {
            int n = i / 5, q = i - n * 5;
            int gn = n0 + n;
            float2 v = make_float2(0, 0);
            if (gn < NN) v = xt2[(size_t)gn * 5 + q];
            *(float2*)&xin[n][20 + q * 2] = v;
        }
        // stage encoder weights: rows 0-7 Wf, 8-19 Ww, 20-29 Wt
        for (int i = t; i < 480; i += 256) {
            int r = i >> 4, q = i & 15;
            float4 v;
            if (r < 8)       v = ((const float4*)Wf)[r * 16 + q];
            else if (r < 20) v = ((const float4*)Ww)[(r - 8) * 16 + q];
            else             v = ((const float4*)Wt)[(r - 20) * 16 + q];
            *(float4*)&wenc[r][q * 4] = v;
        }
        // stage encoder biases
        if (t < 192) bs[t] = (t < 64) ? bf[t] : (t < 128) ? bw[t - 64] : bt[t - 128];
    }

    int cg = t & 15, ng = t >> 4;
    int c0 = cg * 4;
    float4 acc[4];
    #pragma unroll
    for (int i = 0; i < 4; i++) acc[i] = make_float4(0, 0, 0, 0);

    for (int kq = 0; kq < 6; kq++) {
        __syncthreads();
        {   // stage W0 slice rows [kq*32, kq*32+32)
            const float4* W04 = (const float4*)W0;
            float4* ws4 = (float4*)&ws[0][0];
            for (int i = t; i < 512; i += 256)
                ws4[i] = W04[(size_t)kq * 512 + i];
        }
        // compute encoder outputs for this slice (uniform modality per kq)
        int w0r  = (kq < 2) ? 0 : (kq < 4) ? 8 : 20;            // xin/wenc row base
        int coff = (kq < 2) ? kq * 32 : (kq < 4) ? (kq - 2) * 32 : (kq - 4) * 32;
        if (kq < 2) {
            for (int i = t; i < 2048; i += 256) {
                int n = i >> 5, kk = i & 31;
                float a = bs[kq * 32 + kk];
                #pragma unroll
                for (int k = 0; k < 8; k++) a = fmaf(xin[n][k], wenc[k][coff + kk], a);
                xs[n][kk] = fmaxf(a, 0.f);
            }
        } else if (kq < 4) {
            for (int i = t; i < 2048; i += 256) {
                int n = i >> 5, kk = i & 31;
                float a = bs[kq * 32 + kk];
                #pragma unroll
                for (int k = 0; k < 12; k++) a = fmaf(xin[n][8 + k], wenc[8 + k][coff + kk], a);
                xs[n][kk] = fmaxf(a, 0.f);
            }
        } else {
            for (int i = t; i < 2048; i += 256) {
                int n = i >> 5, kk = i & 31;
                float a = bs[kq * 32 + kk];
                #pragma unroll
                for (int k = 0; k < 10; k++) a = fmaf(xin[n][20 + k], wenc[20 + k][coff + kk], a);
                xs[n][kk] = fmaxf(a, 0.f);
            }
        }
        __syncthreads();
        // register-blocked fma over this 32-slice
        for (int k = 0; k < 32; k += 4) {
            float4 b0 = *(const float4*)&ws[k + 0][c0];
            float4 b1 = *(const float4*)&ws[k + 1][c0];
            float4 b2 = *(const float4*)&ws[k + 2][c0];
            float4 b3 = *(const float4*)&ws[k + 3][c0];
            #pragma unroll
            for (int i = 0; i < 4; i++) {
                float4 a = *(const float4*)&xs[ng * 4 + i][k];
                fma4(acc[i], a.x, b0); fma4(acc[i], a.y, b1);
                fma4(acc[i], a.z, b2); fma4(acc[i], a.w, b3);
            }
        }
    }
    float4* h4 = (float4*)h;
    #pragma unroll
    for (int i = 0; i < 4; i++) {
        int gn = n0 + ng * 4 + i;
        if (gn < NN) {
            float dn = dinv[gn];
            float4 v = acc[i];
            v.x *= dn; v.y *= dn; v.z *= dn; v.w *= dn;
            h4[(size_t)gn * 16 + cg] = v;
        }
    }
}

// ---------------- 64x64 matmul, register-blocked: h = (x @ W) * dinv[n] ----
__global__ void __launch_bounds__(256) mm64_kernel(
    const float* __restrict__ x, const float* __restrict__ W,
    const float* __restrict__ dinv, float* __restrict__ h) {
    __shared__ float xs[64][68];
    __shared__ float ws[64][64];
    int t = threadIdx.x;
    int n0 = blockIdx.x * 64;
    {
        const float4* W4 = (const float4*)W;
        float4* ws4 = (float4*)&ws[0][0];
        for (int i = t; i < 1024; i += 256) ws4[i] = W4[i];
        const float4* x4 = (const float4*)x;
        for (int i = t; i < 1024; i += 256) {
            int n = i >> 4, q = i & 15;
            int gn = n0 + n;
            float4 v = make_float4(0, 0, 0, 0);
            if (gn < NN) v = x4[(size_t)gn * 16 + q];
            *(float4*)&xs[n][q * 4] = v;
        }
    }
    __syncthreads();
    int cg = t & 15, ng = t >> 4;
    int c0 = cg * 4;
    float4 acc[4];
    #pragma unroll
    for (int i = 0; i < 4; i++) acc[i] = make_float4(0, 0, 0, 0);
    for (int k = 0; k < 64; k += 4) {
        float4 b0 = *(const float4*)&ws[k + 0][c0];
        float4 b1 = *(const float4*)&ws[k + 1][c0];
        float4 b2 = *(const float4*)&ws[k + 2][c0];
        float4 b3 = *(const float4*)&ws[k + 3][c0];
        #pragma unroll
        for (int i = 0; i < 4; i++) {
            float4 a = *(const float4*)&xs[ng * 4 + i][k];
            fma4(acc[i], a.x, b0); fma4(acc[i], a.y, b1);
            fma4(acc[i], a.z, b2); fma4(acc[i], a.w, b3);
        }
    }
    float4* h4 = (float4*)h;
    #pragma unroll
    for (int i = 0; i < 4; i++) {
        int gn = n0 + ng * 4 + i;
        if (gn < NN) {
            float dn = dinv[gn];
            float4 v = acc[i];
            v.x *= dn; v.y *= dn; v.z *= dn; v.w *= dn;
            h4[(size_t)gn * 16 + cg] = v;
        }
    }
}

// ---------------- CSR gather + finalize ----------------
__global__ void __launch_bounds__(256) gather_kernel(
    const int* __restrict__ col, const int* __restrict__ rowptr,
    const float* __restrict__ dinv, const float* __restrict__ h,
    const float* __restrict__ bias, float* __restrict__ out) {
    int n = (blockIdx.x * blockDim.x + threadIdx.x) >> 6;
    int l = threadIdx.x & 63;
    if (n >= NN) return;
    int g = l >> 4;      // edge sub-slot 0..3
    int q = l & 15;      // float4 slot 0..15
    const float4* h4 = (const float4*)h;
    float4 acc = make_float4(0, 0, 0, 0);
    int r0 = rowptr[n], r1 = rowptr[n + 1];
    for (int base = r0; base < r1; base += 64) {
        int cnt = min(64, r1 - base);
        int pv = NN;                          // sentinel: zero row
        if (l < cnt) pv = __builtin_nontemporal_load(col + base + l);
        int steps = (cnt + 3) >> 2;
        int j = 0;
        for (; j + 4 <= steps; j += 4) {
            int e0 = (j + 0) * 4 + g, e1 = (j + 1) * 4 + g;
            int e2 = (j + 2) * 4 + g, e3 = (j + 3) * 4 + g;
            int s0 = __shfl(pv, e0);
            int s1 = __shfl(pv, e1);
            int s2 = __shfl(pv, e2);
            int s3 = __shfl(pv, e3);
            float4 v0 = h4[(size_t)s0 * 16 + q];
            float4 v1 = h4[(size_t)s1 * 16 + q];
            float4 v2 = h4[(size_t)s2 * 16 + q];
            float4 v3 = h4[(size_t)s3 * 16 + q];
            add4(acc, v0); add4(acc, v1);
            add4(acc, v2); add4(acc, v3);
        }
        for (; j < steps; j++) {
            int e = j * 4 + g;
            int s = __shfl(pv, e);
            float4 v = h4[(size_t)s * 16 + q];
            add4(acc, v);
        }
    }
    acc.x += __shfl_xor(acc.x, 16); acc.y += __shfl_xor(acc.y, 16);
    acc.z += __shfl_xor(acc.z, 16); acc.w += __shfl_xor(acc.w, 16);
    acc.x += __shfl_xor(acc.x, 32); acc.y += __shfl_xor(acc.y, 32);
    acc.z += __shfl_xor(acc.z, 32); acc.w += __shfl_xor(acc.w, 32);
    if (g == 0) {
        float dn = dinv[n];
        float4 hn = h4[(size_t)n * 16 + q];   // hs[n] = h[n]*dinv[n]
        float4 b4 = ((const float4*)bias)[q];
        float4 r;
        r.x = fmaxf(fmaf(dn, acc.x + hn.x, b4.x), 0.f);
        r.y = fmaxf(fmaf(dn, acc.y + hn.y, b4.y), 0.f);
        r.z = fmaxf(fmaf(dn, acc.z + hn.z, b4.z), 0.f);
        r.w = fmaxf(fmaf(dn, acc.w + hn.w, b4.w), 0.f);
        ((float4*)out)[(size_t)n * 16 + q] = r;
    }
}

// ---------------- fused output MLP ----------------
__global__ void __launch_bounds__(256) mlp_kernel(
    const float* __restrict__ x, const float* __restrict__ w1, const float* __restrict__ b1,
    const float* __restrict__ w2, const float* __restrict__ b2, float* __restrict__ out) {
    int t = threadIdx.x;
    int nl = t >> 5, j = t & 31;
    int n = blockIdx.x * 8 + nl;
    float acc = b1[j];
    if (n < NN) {
        #pragma unroll
        for (int k = 0; k < 64; k++) acc = fmaf(x[n * 64 + k], w1[k * 32 + j], acc);
    }
    float hj = fmaxf(acc, 0.f) * w2[j];
    #pragma unroll
    for (int off = 16; off; off >>= 1) hj += __shfl_down(hj, off, 32);
    if (j == 0 && n < NN) out[n] = hj + b2[0];
}

extern "C" void kernel_launch(void* const* d_in, const int* in_sizes, int n_in,
                              void* d_out, int out_size, void* d_ws, size_t ws_size,
                              hipStream_t stream) {
    const float* xf = (const float*)d_in[0];
    const float* xw = (const float*)d_in[1];
    const float* xt = (const float*)d_in[2];
    const int*   ei = (const int*)d_in[3];
    const int*   src = ei;
    const int*   dst = ei + NE;
    const float* Wf = (const float*)d_in[4];
    const float* bf = (const float*)d_in[5];
    const float* Ww = (const float*)d_in[6];
    const float* bw = (const float*)d_in[7];
    const float* Wt = (const float*)d_in[8];
    const float* bt = (const float*)d_in[9];
    const float* W0 = (const float*)d_in[10];
    const float* b0 = (const float*)d_in[11];
    const float* W1 = (const float*)d_in[12];
    const float* b1 = (const float*)d_in[13];
    const float* W2 = (const float*)d_in[14];
    const float* b2 = (const float*)d_in[15];
    const float* ow1 = (const float*)d_in[16];
    const float* ob1 = (const float*)d_in[17];
    const float* ow2 = (const float*)d_in[18];
    const float* ob2 = (const float*)d_in[19];
    float* out = (float*)d_out;

    // workspace layout (~65 MB). pairs (42 MB) ALIASES h+agg: it is dead before
    // encmm0 writes h (stream-ordered after csr_fill reads pairs).
    char* w = (char*)d_ws;
    float* h      = (float*)w;  w += (size_t)(NN + 1) * 64 * 4;      // 25.6 MB (+zero row)
    float* agg    = (float*)w;  w += (size_t)NN * 64 * 4;            // 25.6 MB
    int*   col    = (int*)w;    w += (size_t)NE * 4;                 // 12.8 MB
    v2i*   povf   = (v2i*)w;    w += (size_t)NBUCK * OVFCAP * 8;     // 1 MB
    float* dinv   = (float*)w;  w += (size_t)NN * 4;
    int*   rowptr = (int*)w;    w += (size_t)(NN + 1) * 4;
    int*   bctl   = (int*)w;    w += (size_t)NBUCK * 16 * 4;         // 16 KB (padded lines)
    int*   bbase  = (int*)w;    w += (size_t)NBUCK * 4;
    v2i*   pairs  = (v2i*)h;                                         // alias (42 MB <= 51.2 MB)

    // ---- CSR build (two-phase, line-staged; reused by all 3 layers) ----
    hipMemsetAsync(bctl, 0, (size_t)NBUCK * 16 * 4, stream);
    partition_kernel<<<P1_GRID, 256, 0, stream>>>(src, dst, bctl, pairs, povf);
    bucket_scan_kernel<<<1, NBUCK, 0, stream>>>(bctl, bbase, rowptr);
    csr_fill_kernel<<<NBUCK, 256, 0, stream>>>(pairs, povf, bctl, bbase, rowptr, dinv, col);
    hipMemsetAsync(h + (size_t)NN * 64, 0, 64 * 4, stream);   // sentinel zero row (after pairs dead)

    // ---- layer 0: fused encoders + matmul (scaled), then gather+finalize ----
    encmm0_kernel<<<(NN + 63) / 64, 256, 0, stream>>>(xf, xw, xt, Wf, bf, Ww, bw, Wt, bt, W0, dinv, h);
    gather_kernel<<<(NN * 64 + 255) / 256, 256, 0, stream>>>(col, rowptr, dinv, h, b0, agg);

    // ---- layer 1 ----
    mm64_kernel<<<(NN + 63) / 64, 256, 0, stream>>>(agg, W1, dinv, h);
    gather_kernel<<<(NN * 64 + 255) / 256, 256, 0, stream>>>(col, rowptr, dinv, h, b1, agg);

    // ---- layer 2 ----
    mm64_kernel<<<(NN + 63) / 64, 256, 0, stream>>>(agg, W2, dinv, h);
    gather_kernel<<<(NN * 64 + 255) / 256, 256, 0, stream>>>(col, rowptr, dinv, h, b2, agg);

    // ---- output MLP ----
    mlp_kernel<<<(NN + 7) / 8, 256, 0, stream>>>(agg, ow1, ob1, ow2, ob2, out);
}

// Round 8
// 683.309 us; speedup vs baseline: 1.1738x; 1.0158x over previous
//
#include <hip/hip_runtime.h>

#define NN 100000
#define NE 3200000
#define HD 64

// two-phase CSR build
#define NBUCK 256
#define BWID 392                                    // 256*392 = 100352 >= NN
#define SLACK 20480                                 // slots/bucket: 12544 real + ~5500 pad + margin
#define COLCAP 13568                                // real cols/bucket cap (12544 + ~9 sigma)
#define OVFCAP 512                                  // overflow pairs/bucket
#define CAP 16                                      // staged pairs per bucket per block
#define P1_EPB 2048                                 // edges per partition block
#define P1_GRID ((NE + P1_EPB - 1) / P1_EPB)        // 1563

typedef int   v4i __attribute__((ext_vector_type(4)));
typedef int   v2i __attribute__((ext_vector_type(2)));

__device__ __forceinline__ void fma4(float4& a, float s, const float4& b) {
    a.x = fmaf(s, b.x, a.x); a.y = fmaf(s, b.y, a.y);
    a.z = fmaf(s, b.z, a.z); a.w = fmaf(s, b.w, a.w);
}
__device__ __forceinline__ void add4(float4& a, const float4& b) {
    a.x += b.x; a.y += b.y; a.z += b.z; a.w += b.w;
}

// ---------------- phase 1: bucket partition, LDS-staged, 1 drain/block ----------------
__global__ void __launch_bounds__(256) partition_kernel(
    const int* __restrict__ src, const int* __restrict__ dst,
    int* __restrict__ bctl, v2i* __restrict__ pairs, v2i* __restrict__ povf) {
    __shared__ v2i stage[NBUCK][CAP];
    __shared__ int cnt[NBUCK];
    int t = threadIdx.x;
    cnt[t] = 0;                         // NBUCK == blockDim == 256
    __syncthreads();
    const v4i* d4p = (const v4i*)dst;
    const v4i* s4p = (const v4i*)src;
    const int NE4 = NE / 4;
    int base4 = blockIdx.x * (P1_EPB / 4);
    #pragma unroll
    for (int it = 0; it < P1_EPB / 1024; it++) {
        int i = base4 + it * 256 + t;
        v4i d4 = (v4i){-1, -1, -1, -1};
        v4i s4 = (v4i){0, 0, 0, 0};
        if (i < NE4) {
            d4 = __builtin_nontemporal_load(d4p + i);
            s4 = __builtin_nontemporal_load(s4p + i);
        }
        #pragma unroll
        for (int k = 0; k < 4; k++) {
            int d = d4[k];
            if (d >= 0) {
                int b = (unsigned)d / BWID;
                int slot = atomicAdd(&cnt[b], 1);
                v2i p; p[0] = s4[k]; p[1] = d;
                if (slot < CAP) {
                    stage[b][slot] = p;
                } else {                 // rare overflow -> separate region
                    int o = atomicAdd(&bctl[b * 16 + 2], 1);
                    if (o < OVFCAP) povf[(size_t)b * OVFCAP + o] = p;
                }
            }
        }
    }
    __syncthreads();
    // drain bucket t (single drain per block)
    int c_tot = cnt[t];
    int c = (c_tot > CAP) ? CAP : c_tot;
    int runs = (c + 7) >> 3;             // 0..2
    if (runs) {
        int slots = runs * 8;            // 8 or 16, <= CAP
        for (int m = c; m < slots; m++) { v2i p; p[0] = 0; p[1] = -1; stage[t][m] = p; }
        int gb = atomicAdd(&bctl[t * 16], slots);   // stays multiple of 8
        if (gb + slots <= SLACK) {
            v4i* gp = (v4i*)(pairs + (size_t)t * SLACK + gb);
            const v4i* sp = (const v4i*)&stage[t][0];
            #pragma unroll
            for (int m = 0; m < 8; m++) { if (m < runs * 4) gp[m] = sp[m]; }
        } else {
            for (int m = 0; m < slots && gb + m < SLACK; m++)
                pairs[(size_t)t * SLACK + gb + m] = stage[t][m];
        }
    }
    if (c_tot > 0) atomicAdd(&bctl[t * 16 + 1], c_tot);   // real contribution
}

// ---------------- tiny scan over real bucket counts ----------------
__global__ void bucket_scan_kernel(const int* __restrict__ bctl,
                                   int* __restrict__ bbase, int* __restrict__ rowptr) {
    __shared__ int s[NBUCK];
    int t = threadIdx.x;
    int v = bctl[t * 16 + 1];
    s[t] = v; __syncthreads();
    for (int off = 1; off < NBUCK; off <<= 1) {
        int x = (t >= off) ? s[t - off] : 0;
        __syncthreads();
        s[t] += x;
        __syncthreads();
    }
    bbase[t] = s[t] - v;                 // exclusive prefix of real counts
    if (t == NBUCK - 1) rowptr[NN] = s[t];   // == NE
}

// ---------------- phase 2: per-bucket hist + scan + LDS scatter ----------------
__global__ void __launch_bounds__(256) csr_fill_kernel(
    const v2i* __restrict__ pairs, const v2i* __restrict__ povf,
    const int* __restrict__ bctl, const int* __restrict__ bbase,
    int* __restrict__ rowptr, float* __restrict__ dinv, int* __restrict__ col) {
    __shared__ int hist[BWID];
    __shared__ int rp[BWID];
    __shared__ int cur[BWID];
    __shared__ int sc[256];
    __shared__ int cols[COLCAP];
    int b = blockIdx.x, t = threadIdx.x;
    int lo = b * BWID;
    int hi = min(lo + BWID, NN);
    int nw = hi - lo;
    for (int i = t; i < BWID; i += 256) { hist[i] = 0; cur[i] = 0; }
    __syncthreads();
    int np = bctl[b * 16];     if (np > SLACK) np = SLACK;
    int nov = bctl[b * 16 + 2]; if (nov > OVFCAP) nov = OVFCAP;
    int base = bbase[b];
    const v2i* pb = pairs + (size_t)b * SLACK;
    const v2i* ob = povf + (size_t)b * OVFCAP;
    // pass 1: histogram (skip sentinels)
    for (int i = t; i < np; i += 256) {
        v2i p = pb[i];
        if (p[1] >= 0) atomicAdd(&hist[p[1] - lo], 1);
    }
    for (int i = t; i < nov; i += 256) {
        v2i p = ob[i];
        atomicAdd(&hist[p[1] - lo], 1);
    }
    __syncthreads();
    // exclusive scan of hist -> rp (2 elements per thread)
    int h0 = 0, s2 = 0;
    if (2 * t < BWID) {
        h0 = hist[2 * t];
        int h1 = (2 * t + 1 < BWID) ? hist[2 * t + 1] : 0;
        s2 = h0 + h1;
    }
    sc[t] = s2; __syncthreads();
    for (int off = 1; off < 256; off <<= 1) {
        int x = (t >= off) ? sc[t - off] : 0;
        __syncthreads();
        sc[t] += x;
        __syncthreads();
    }
    if (2 * t < BWID) {
        int ex = sc[t] - s2;
        rp[2 * t] = ex;
        if (2 * t + 1 < BWID) rp[2 * t + 1] = ex + h0;
    }
    __syncthreads();
    // rowptr + dinv slices (coalesced)
    for (int i = t; i < nw; i += 256) {
        rowptr[lo + i] = base + rp[i];
        dinv[lo + i] = 1.0f / sqrtf((float)(hist[i] + 1));  // +1 self-loop
    }
    // pass 2: scatter into LDS
    for (int i = t; i < np; i += 256) {
        v2i p = pb[i];
        if (p[1] >= 0) {
            int li = p[1] - lo;
            int slot = atomicAdd(&cur[li], 1);
            int o = rp[li] + slot;
            if (o < COLCAP) cols[o] = p[0];
        }
    }
    for (int i = t; i < nov; i += 256) {
        v2i p = ob[i];
        int li = p[1] - lo;
        int slot = atomicAdd(&cur[li], 1);
        int o = rp[li] + slot;
        if (o < COLCAP) cols[o] = p[0];
    }
    __syncthreads();
    // contiguous col write (real count only)
    int nreal = bctl[b * 16 + 1]; if (nreal > COLCAP) nreal = COLCAP;
    for (int i = t; i < nreal; i += 256)
        col[base + i] = cols[i];
}

// ---------------- fused modality encoders + GCN layer-0 matmul ----------------
__global__ void __launch_bounds__(256) encmm0_kernel(
    const float* __restrict__ xf, const float* __restrict__ xw, const float* __restrict__ xt,
    const float* __restrict__ Wf, const float* __restrict__ bf,
    const float* __restrict__ Ww, const float* __restrict__ bw,
    const float* __restrict__ Wt, const float* __restrict__ bt,
    const float* __restrict__ W0, const float* __restrict__ dinv,
    float* __restrict__ h) {
    __shared__ float xin[64][32];    // fire[0..7], wea[8..19], ter[20..29]
    __shared__ float wenc[30][64];   // encoder weights (rows match xin cols)
    __shared__ float bs[192];        // encoder biases
    __shared__ float xs[64][36];     // encoder outputs for current 32-slice (+4 pad)
    __shared__ float ws[32][64];     // W0 rows for current slice
    int t = threadIdx.x;
    int n0 = blockIdx.x * 64;

    {   // stage raw inputs
        const float4* xf4 = (const float4*)xf;
        for (int i = t; i < 128; i += 256) {
            int n = i >> 1, q = i & 1;
            int gn = n0 + n;
            float4 v = make_float4(0, 0, 0, 0);
            if (gn < NN) v = xf4[(size_t)gn * 2 + q];
            *(float4*)&xin[n][q * 4] = v;
        }
        const float4* xw4 = (const float4*)xw;
        for (int i = t; i < 192; i += 256) {
            int n = i / 3, q = i - n * 3;
            int gn = n0 + n;
            float4 v = make_float4(0, 0, 0, 0);
            if (gn < NN) v = xw4[(size_t)gn * 3 + q];
            *(float4*)&xin[n][8 + q * 4] = v;
        }
        const float2* xt2 = (const float2*)xt;
        for (int i = t; i < 320; i += 256) {
            int n = i / 5, q = i - n * 5;
            int gn = n0 + n;
            float2 v = make_float2(0, 0);
            if (gn < NN) v = xt2[(size_t)gn * 5 + q];
            *(float2*)&xin[n][20 + q * 2] = v;
        }
        // stage encoder weights: rows 0-7 Wf, 8-19 Ww, 20-29 Wt
        for (int i = t; i < 480; i += 256) {
            int r = i >> 4, q = i & 15;
            float4 v;
            if (r < 8)       v = ((const float4*)Wf)[r * 16 + q];
            else if (r < 20) v = ((const float4*)Ww)[(r - 8) * 16 + q];
            else             v = ((const float4*)Wt)[(r - 20) * 16 + q];
            *(float4*)&wenc[r][q * 4] = v;
        }
        // stage encoder biases
        if (t < 192) bs[t] = (t < 64) ? bf[t] : (t < 128) ? bw[t - 64] : bt[t - 128];
    }

    int cg = t & 15, ng = t >> 4;
    int c0 = cg * 4;
    float4 acc[4];
    #pragma unroll
    for (int i = 0; i < 4; i++) acc[i] = make_float4(0, 0, 0, 0);

    for (int kq = 0; kq < 6; kq++) {
        __syncthreads();
        {   // stage W0 slice rows [kq*32, kq*32+32)
            const float4* W04 = (const float4*)W0;
            float4* ws4 = (float4*)&ws[0][0];
            for (int i = t; i < 512; i += 256)
                ws4[i] = W04[(size_t)kq * 512 + i];
        }
        // compute encoder outputs for this slice (uniform modality per kq)
        int coff = (kq < 2) ? kq * 32 : (kq < 4) ? (kq - 2) * 32 : (kq - 4) * 32;
        if (kq < 2) {
            for (int i = t; i < 2048; i += 256) {
                int n = i >> 5, kk = i & 31;
                float a = bs[kq * 32 + kk];
                #pragma unroll
                for (int k = 0; k < 8; k++) a = fmaf(xin[n][k], wenc[k][coff + kk], a);
                xs[n][kk] = fmaxf(a, 0.f);
            }
        } else if (kq < 4) {
            for (int i = t; i < 2048; i += 256) {
                int n = i >> 5, kk = i & 31;
                float a = bs[kq * 32 + kk];
                #pragma unroll
                for (int k = 0; k < 12; k++) a = fmaf(xin[n][8 + k], wenc[8 + k][coff + kk], a);
                xs[n][kk] = fmaxf(a, 0.f);
            }
        } else {
            for (int i = t; i < 2048; i += 256) {
                int n = i >> 5, kk = i & 31;
                float a = bs[kq * 32 + kk];
                #pragma unroll
                for (int k = 0; k < 10; k++) a = fmaf(xin[n][20 + k], wenc[20 + k][coff + kk], a);
                xs[n][kk] = fmaxf(a, 0.f);
            }
        }
        __syncthreads();
        // register-blocked fma over this 32-slice
        for (int k = 0; k < 32; k += 4) {
            float4 b0 = *(const float4*)&ws[k + 0][c0];
            float4 b1 = *(const float4*)&ws[k + 1][c0];
            float4 b2 = *(const float4*)&ws[k + 2][c0];
            float4 b3 = *(const float4*)&ws[k + 3][c0];
            #pragma unroll
            for (int i = 0; i < 4; i++) {
                float4 a = *(const float4*)&xs[ng * 4 + i][k];
                fma4(acc[i], a.x, b0); fma4(acc[i], a.y, b1);
                fma4(acc[i], a.z, b2); fma4(acc[i], a.w, b3);
            }
        }
    }
    float4* h4 = (float4*)h;
    #pragma unroll
    for (int i = 0; i < 4; i++) {
        int gn = n0 + ng * 4 + i;
        if (gn < NN) {
            float dn = dinv[gn];
            float4 v = acc[i];
            v.x *= dn; v.y *= dn; v.z *= dn; v.w *= dn;
            h4[(size_t)gn * 16 + cg] = v;
        }
    }
}

// ---------------- fused CSR gather + finalize + next-layer 64x64 matmul ----------------
// Gather phase as before (h rows pre-scaled by dinv -> unweighted edges).
// After the xor-reductions ALL 64 lanes hold the full node row (q = l&15,
// replicated x4), so the relu'd layer output r is computed on every lane.
// Then: broadcast r via shuffles, each lane computes ONE output column of
// r @ W (W staged in LDS, reads are 2 lanes/bank = conflict-free), scales by
// dinv and writes a coalesced 256 B row of the next h. Kills mm64 + agg I/O.
__global__ void __launch_bounds__(256) gather_mm_kernel(
    const int* __restrict__ col, const int* __restrict__ rowptr,
    const float* __restrict__ dinv, const float* __restrict__ h,
    const float* __restrict__ bias, const float* __restrict__ W,
    float* __restrict__ hout) {
    __shared__ float Wl[64][64];
    int t = threadIdx.x;
    {
        const float4* W4 = (const float4*)W;
        float4* wl4 = (float4*)&Wl[0][0];
        for (int i = t; i < 1024; i += 256) wl4[i] = W4[i];
    }
    __syncthreads();
    int n = (blockIdx.x * 256 + t) >> 6;
    int l = t & 63;
    if (n >= NN) return;
    int g = l >> 4;      // edge sub-slot 0..3
    int q = l & 15;      // float4 slot 0..15
    const float4* h4 = (const float4*)h;
    float4 acc = make_float4(0, 0, 0, 0);
    int r0 = rowptr[n], r1 = rowptr[n + 1];
    for (int base = r0; base < r1; base += 64) {
        int cnt = min(64, r1 - base);
        int pv = NN;                          // sentinel: zero row
        if (l < cnt) pv = __builtin_nontemporal_load(col + base + l);
        int steps = (cnt + 3) >> 2;
        int j = 0;
        for (; j + 4 <= steps; j += 4) {
            int e0 = (j + 0) * 4 + g, e1 = (j + 1) * 4 + g;
            int e2 = (j + 2) * 4 + g, e3 = (j + 3) * 4 + g;
            int s0 = __shfl(pv, e0);
            int s1 = __shfl(pv, e1);
            int s2 = __shfl(pv, e2);
            int s3 = __shfl(pv, e3);
            float4 v0 = h4[(size_t)s0 * 16 + q];
            float4 v1 = h4[(size_t)s1 * 16 + q];
            float4 v2 = h4[(size_t)s2 * 16 + q];
            float4 v3 = h4[(size_t)s3 * 16 + q];
            add4(acc, v0); add4(acc, v1);
            add4(acc, v2); add4(acc, v3);
        }
        for (; j < steps; j++) {
            int e = j * 4 + g;
            int s = __shfl(pv, e);
            float4 v = h4[(size_t)s * 16 + q];
            add4(acc, v);
        }
    }
    acc.x += __shfl_xor(acc.x, 16); acc.y += __shfl_xor(acc.y, 16);
    acc.z += __shfl_xor(acc.z, 16); acc.w += __shfl_xor(acc.w, 16);
    acc.x += __shfl_xor(acc.x, 32); acc.y += __shfl_xor(acc.y, 32);
    acc.z += __shfl_xor(acc.z, 32); acc.w += __shfl_xor(acc.w, 32);
    // layer output r (all lanes; q-slot replicated)
    float dn = dinv[n];
    float4 hn = h4[(size_t)n * 16 + q];   // hs[n] = h[n]*dinv[n]
    float4 b4 = ((const float4*)bias)[q];
    float4 r;
    r.x = fmaxf(fmaf(dn, acc.x + hn.x, b4.x), 0.f);
    r.y = fmaxf(fmaf(dn, acc.y + hn.y, b4.y), 0.f);
    r.z = fmaxf(fmaf(dn, acc.z + hn.z, b4.z), 0.f);
    r.w = fmaxf(fmaf(dn, acc.w + hn.w, b4.w), 0.f);
    // next-layer matmul: lane l computes output column l
    float oc = 0.f;
    #pragma unroll
    for (int qq = 0; qq < 16; qq++) {
        float rx = __shfl(r.x, qq);
        float ry = __shfl(r.y, qq);
        float rz = __shfl(r.z, qq);
        float rw = __shfl(r.w, qq);
        oc = fmaf(rx, Wl[qq * 4 + 0][l], oc);
        oc = fmaf(ry, Wl[qq * 4 + 1][l], oc);
        oc = fmaf(rz, Wl[qq * 4 + 2][l], oc);
        oc = fmaf(rw, Wl[qq * 4 + 3][l], oc);
    }
    hout[(size_t)n * 64 + l] = oc * dn;   // pre-scaled for next gather
}

// ---------------- fused CSR gather + finalize + output MLP ----------------
// Same gather; tail computes relu(r @ ow1 + ob1) @ ow2 + ob2 per node.
// Lane l computes hidden unit c = l&31 (lanes 32-63 duplicate); xor-reduce
// over 32 lanes; lane 0 writes the scalar.
__global__ void __launch_bounds__(256) gather_mlp_kernel(
    const int* __restrict__ col, const int* __restrict__ rowptr,
    const float* __restrict__ dinv, const float* __restrict__ h,
    const float* __restrict__ bias, const float* __restrict__ w1,
    const float* __restrict__ b1, const float* __restrict__ w2,
    const float* __restrict__ b2, float* __restrict__ out) {
    __shared__ float W1l[64][32];   // lane c reads W1l[k][c]: distinct banks
    __shared__ float w2l[32];
    __shared__ float b1l[32];
    int t = threadIdx.x;
    {
        const float4* w14 = (const float4*)w1;
        float4* wl4 = (float4*)&W1l[0][0];
        for (int i = t; i < 512; i += 256) wl4[i] = w14[i];
        if (t < 32) { w2l[t] = w2[t]; b1l[t] = b1[t]; }
    }
    __syncthreads();
    int n = (blockIdx.x * 256 + t) >> 6;
    int l = t & 63;
    if (n >= NN) return;
    int g = l >> 4;
    int q = l & 15;
    const float4* h4 = (const float4*)h;
    float4 acc = make_float4(0, 0, 0, 0);
    int r0 = rowptr[n], r1 = rowptr[n + 1];
    for (int base = r0; base < r1; base += 64) {
        int cnt = min(64, r1 - base);
        int pv = NN;
        if (l < cnt) pv = __builtin_nontemporal_load(col + base + l);
        int steps = (cnt + 3) >> 2;
        int j = 0;
        for (; j + 4 <= steps; j += 4) {
            int e0 = (j + 0) * 4 + g, e1 = (j + 1) * 4 + g;
            int e2 = (j + 2) * 4 + g, e3 = (j + 3) * 4 + g;
            int s0 = __shfl(pv, e0);
            int s1 = __shfl(pv, e1);
            int s2 = __shfl(pv, e2);
            int s3 = __shfl(pv, e3);
            float4 v0 = h4[(size_t)s0 * 16 + q];
            float4 v1 = h4[(size_t)s1 * 16 + q];
            float4 v2 = h4[(size_t)s2 * 16 + q];
            float4 v3 = h4[(size_t)s3 * 16 + q];
            add4(acc, v0); add4(acc, v1);
            add4(acc, v2); add4(acc, v3);
        }
        for (; j < steps; j++) {
            int e = j * 4 + g;
            int s = __shfl(pv, e);
            float4 v = h4[(size_t)s * 16 + q];
            add4(acc, v);
        }
    }
    acc.x += __shfl_xor(acc.x, 16); acc.y += __shfl_xor(acc.y, 16);
    acc.z += __shfl_xor(acc.z, 16); acc.w += __shfl_xor(acc.w, 16);
    acc.x += __shfl_xor(acc.x, 32); acc.y += __shfl_xor(acc.y, 32);
    acc.z += __shfl_xor(acc.z, 32); acc.w += __shfl_xor(acc.w, 32);
    float dn = dinv[n];
    float4 hn = h4[(size_t)n * 16 + q];
    float4 b4 = ((const float4*)bias)[q];
    float4 r;
    r.x = fmaxf(fmaf(dn, acc.x + hn.x, b4.x), 0.f);
    r.y = fmaxf(fmaf(dn, acc.y + hn.y, b4.y), 0.f);
    r.z = fmaxf(fmaf(dn, acc.z + hn.z, b4.z), 0.f);
    r.w = fmaxf(fmaf(dn, acc.w + hn.w, b4.w), 0.f);
    // output MLP: hidden unit c = l&31
    int c = l & 31;
    float a2 = b1l[c];
    #pragma unroll
    for (int qq = 0; qq < 16; qq++) {
        float rx = __shfl(r.x, qq);
        float ry = __shfl(r.y, qq);
        float rz = __shfl(r.z, qq);
        float rw = __shfl(r.w, qq);
        a2 = fmaf(rx, W1l[qq * 4 + 0][c], a2);
        a2 = fmaf(ry, W1l[qq * 4 + 1][c], a2);
        a2 = fmaf(rz, W1l[qq * 4 + 2][c], a2);
        a2 = fmaf(rw, W1l[qq * 4 + 3][c], a2);
    }
    float v = fmaxf(a2, 0.f) * w2l[c];
    v += __shfl_xor(v, 1); v += __shfl_xor(v, 2);
    v += __shfl_xor(v, 4); v += __shfl_xor(v, 8);
    v += __shfl_xor(v, 16);
    if (l == 0) out[n] = v + b2[0];
}

extern "C" void kernel_launch(void* const* d_in, const int* in_sizes, int n_in,
                              void* d_out, int out_size, void* d_ws, size_t ws_size,
                              hipStream_t stream) {
    const float* xf = (const float*)d_in[0];
    const float* xw = (const float*)d_in[1];
    const float* xt = (const float*)d_in[2];
    const int*   ei = (const int*)d_in[3];
    const int*   src = ei;
    const int*   dst = ei + NE;
    const float* Wf = (const float*)d_in[4];
    const float* bf = (const float*)d_in[5];
    const float* Ww = (const float*)d_in[6];
    const float* bw = (const float*)d_in[7];
    const float* Wt = (const float*)d_in[8];
    const float* bt = (const float*)d_in[9];
    const float* W0 = (const float*)d_in[10];
    const float* b0 = (const float*)d_in[11];
    const float* W1 = (const float*)d_in[12];
    const float* b1 = (const float*)d_in[13];
    const float* W2 = (const float*)d_in[14];
    const float* b2 = (const float*)d_in[15];
    const float* ow1 = (const float*)d_in[16];
    const float* ob1 = (const float*)d_in[17];
    const float* ow2 = (const float*)d_in[18];
    const float* ob2 = (const float*)d_in[19];
    float* out = (float*)d_out;

    // workspace layout. pairs (42 MB) ALIASES hA+hB: dead before encmm0 writes hA.
    char* w = (char*)d_ws;
    float* hA     = (float*)w;  w += (size_t)(NN + 1) * 64 * 4;      // 25.6 MB (+zero row)
    float* hB     = (float*)w;  w += (size_t)(NN + 1) * 64 * 4;      // 25.6 MB (+zero row)
    int*   col    = (int*)w;    w += (size_t)NE * 4;                 // 12.8 MB
    v2i*   povf   = (v2i*)w;    w += (size_t)NBUCK * OVFCAP * 8;     // 1 MB
    float* dinv   = (float*)w;  w += (size_t)NN * 4;
    int*   rowptr = (int*)w;    w += (size_t)(NN + 1) * 4;
    int*   bctl   = (int*)w;    w += (size_t)NBUCK * 16 * 4;         // 16 KB (padded lines)
    int*   bbase  = (int*)w;    w += (size_t)NBUCK * 4;
    v2i*   pairs  = (v2i*)hA;                                        // alias (42 MB <= 51.2 MB)

    // ---- CSR build (two-phase, line-staged; reused by all 3 layers) ----
    hipMemsetAsync(bctl, 0, (size_t)NBUCK * 16 * 4, stream);
    partition_kernel<<<P1_GRID, 256, 0, stream>>>(src, dst, bctl, pairs, povf);
    bucket_scan_kernel<<<1, NBUCK, 0, stream>>>(bctl, bbase, rowptr);
    csr_fill_kernel<<<NBUCK, 256, 0, stream>>>(pairs, povf, bctl, bbase, rowptr, dinv, col);
    // sentinel zero rows (after pairs is dead)
    hipMemsetAsync(hA + (size_t)NN * 64, 0, 64 * 4, stream);
    hipMemsetAsync(hB + (size_t)NN * 64, 0, 64 * 4, stream);

    // ---- layer 0: fused encoders + matmul (scaled) -> hA ----
    encmm0_kernel<<<(NN + 63) / 64, 256, 0, stream>>>(xf, xw, xt, Wf, bf, Ww, bw, Wt, bt, W0, dinv, hA);
    // ---- gather(b0) + mm(W1) : hA -> hB ----
    gather_mm_kernel<<<NN / 4, 256, 0, stream>>>(col, rowptr, dinv, hA, b0, W1, hB);
    // ---- gather(b1) + mm(W2) : hB -> hA ----
    gather_mm_kernel<<<NN / 4, 256, 0, stream>>>(col, rowptr, dinv, hB, b1, W2, hA);
    // ---- gather(b2) + output MLP : hA -> out ----
    gather_mlp_kernel<<<NN / 4, 256, 0, stream>>>(col, rowptr, dinv, hA, b2, ow1, ob1, ow2, ob2, out);
}

// Round 9
// 677.444 us; speedup vs baseline: 1.1840x; 1.0087x over previous
//
#include <hip/hip_runtime.h>

#define NN 100000
#define NE 3200000
#define HD 64

// two-phase CSR build
#define NBUCK 256
#define BWID 392                                    // 256*392 = 100352 >= NN
#define SLACK 20480                                 // slots/bucket: 12544 real + ~5500 pad + margin
#define COLCAP 13568                                // real cols/bucket cap (12544 + ~9 sigma)
#define OVFCAP 512                                  // overflow pairs/bucket
#define CAP 16                                      // staged pairs per bucket per block
#define P1_EPB 2048                                 // edges per partition block
#define P1_GRID ((NE + P1_EPB - 1) / P1_EPB)        // 1563

#define GB 2048                                     // gather grid (8 blocks/CU)

typedef int   v4i __attribute__((ext_vector_type(4)));
typedef int   v2i __attribute__((ext_vector_type(2)));

__device__ __forceinline__ void fma4(float4& a, float s, const float4& b) {
    a.x = fmaf(s, b.x, a.x); a.y = fmaf(s, b.y, a.y);
    a.z = fmaf(s, b.z, a.z); a.w = fmaf(s, b.w, a.w);
}
__device__ __forceinline__ void add4(float4& a, const float4& b) {
    a.x += b.x; a.y += b.y; a.z += b.z; a.w += b.w;
}

// ---------------- phase 1: bucket partition, LDS-staged, 1 drain/block ----------------
__global__ void __launch_bounds__(256) partition_kernel(
    const int* __restrict__ src, const int* __restrict__ dst,
    int* __restrict__ bctl, v2i* __restrict__ pairs, v2i* __restrict__ povf) {
    __shared__ v2i stage[NBUCK][CAP];
    __shared__ int cnt[NBUCK];
    int t = threadIdx.x;
    cnt[t] = 0;                         // NBUCK == blockDim == 256
    __syncthreads();
    const v4i* d4p = (const v4i*)dst;
    const v4i* s4p = (const v4i*)src;
    const int NE4 = NE / 4;
    int base4 = blockIdx.x * (P1_EPB / 4);
    #pragma unroll
    for (int it = 0; it < P1_EPB / 1024; it++) {
        int i = base4 + it * 256 + t;
        v4i d4 = (v4i){-1, -1, -1, -1};
        v4i s4 = (v4i){0, 0, 0, 0};
        if (i < NE4) {
            d4 = __builtin_nontemporal_load(d4p + i);
            s4 = __builtin_nontemporal_load(s4p + i);
        }
        #pragma unroll
        for (int k = 0; k < 4; k++) {
            int d = d4[k];
            if (d >= 0) {
                int b = (unsigned)d / BWID;
                int slot = atomicAdd(&cnt[b], 1);
                v2i p; p[0] = s4[k]; p[1] = d;
                if (slot < CAP) {
                    stage[b][slot] = p;
                } else {                 // rare overflow -> separate region
                    int o = atomicAdd(&bctl[b * 16 + 2], 1);
                    if (o < OVFCAP) povf[(size_t)b * OVFCAP + o] = p;
                }
            }
        }
    }
    __syncthreads();
    // drain bucket t (single drain per block)
    int c_tot = cnt[t];
    int c = (c_tot > CAP) ? CAP : c_tot;
    int runs = (c + 7) >> 3;             // 0..2
    if (runs) {
        int slots = runs * 8;            // 8 or 16, <= CAP
        for (int m = c; m < slots; m++) { v2i p; p[0] = 0; p[1] = -1; stage[t][m] = p; }
        int gb = atomicAdd(&bctl[t * 16], slots);   // stays multiple of 8
        if (gb + slots <= SLACK) {
            v4i* gp = (v4i*)(pairs + (size_t)t * SLACK + gb);
            const v4i* sp = (const v4i*)&stage[t][0];
            #pragma unroll
            for (int m = 0; m < 8; m++) { if (m < runs * 4) gp[m] = sp[m]; }
        } else {
            for (int m = 0; m < slots && gb + m < SLACK; m++)
                pairs[(size_t)t * SLACK + gb + m] = stage[t][m];
        }
    }
    if (c_tot > 0) atomicAdd(&bctl[t * 16 + 1], c_tot);   // real contribution
}

// ---------------- tiny scan over real bucket counts ----------------
__global__ void bucket_scan_kernel(const int* __restrict__ bctl,
                                   int* __restrict__ bbase, int* __restrict__ rowptr) {
    __shared__ int s[NBUCK];
    int t = threadIdx.x;
    int v = bctl[t * 16 + 1];
    s[t] = v; __syncthreads();
    for (int off = 1; off < NBUCK; off <<= 1) {
        int x = (t >= off) ? s[t - off] : 0;
        __syncthreads();
        s[t] += x;
        __syncthreads();
    }
    bbase[t] = s[t] - v;                 // exclusive prefix of real counts
    if (t == NBUCK - 1) rowptr[NN] = s[t];   // == NE
}

// ---------------- phase 2: per-bucket hist + scan + LDS scatter ----------------
__global__ void __launch_bounds__(256) csr_fill_kernel(
    const v2i* __restrict__ pairs, const v2i* __restrict__ povf,
    const int* __restrict__ bctl, const int* __restrict__ bbase,
    int* __restrict__ rowptr, float* __restrict__ dinv, int* __restrict__ col) {
    __shared__ int hist[BWID];
    __shared__ int rp[BWID];
    __shared__ int cur[BWID];
    __shared__ int sc[256];
    __shared__ int cols[COLCAP];
    int b = blockIdx.x, t = threadIdx.x;
    int lo = b * BWID;
    int hi = min(lo + BWID, NN);
    int nw = hi - lo;
    for (int i = t; i < BWID; i += 256) { hist[i] = 0; cur[i] = 0; }
    __syncthreads();
    int np = bctl[b * 16];     if (np > SLACK) np = SLACK;
    int nov = bctl[b * 16 + 2]; if (nov > OVFCAP) nov = OVFCAP;
    int base = bbase[b];
    const v2i* pb = pairs + (size_t)b * SLACK;
    const v2i* ob = povf + (size_t)b * OVFCAP;
    // pass 1: histogram (skip sentinels)
    for (int i = t; i < np; i += 256) {
        v2i p = pb[i];
        if (p[1] >= 0) atomicAdd(&hist[p[1] - lo], 1);
    }
    for (int i = t; i < nov; i += 256) {
        v2i p = ob[i];
        atomicAdd(&hist[p[1] - lo], 1);
    }
    __syncthreads();
    // exclusive scan of hist -> rp (2 elements per thread)
    int h0 = 0, s2 = 0;
    if (2 * t < BWID) {
        h0 = hist[2 * t];
        int h1 = (2 * t + 1 < BWID) ? hist[2 * t + 1] : 0;
        s2 = h0 + h1;
    }
    sc[t] = s2; __syncthreads();
    for (int off = 1; off < 256; off <<= 1) {
        int x = (t >= off) ? sc[t - off] : 0;
        __syncthreads();
        sc[t] += x;
        __syncthreads();
    }
    if (2 * t < BWID) {
        int ex = sc[t] - s2;
        rp[2 * t] = ex;
        if (2 * t + 1 < BWID) rp[2 * t + 1] = ex + h0;
    }
    __syncthreads();
    // rowptr + dinv slices (coalesced)
    for (int i = t; i < nw; i += 256) {
        rowptr[lo + i] = base + rp[i];
        dinv[lo + i] = 1.0f / sqrtf((float)(hist[i] + 1));  // +1 self-loop
    }
    // pass 2: scatter into LDS
    for (int i = t; i < np; i += 256) {
        v2i p = pb[i];
        if (p[1] >= 0) {
            int li = p[1] - lo;
            int slot = atomicAdd(&cur[li], 1);
            int o = rp[li] + slot;
            if (o < COLCAP) cols[o] = p[0];
        }
    }
    for (int i = t; i < nov; i += 256) {
        v2i p = ob[i];
        int li = p[1] - lo;
        int slot = atomicAdd(&cur[li], 1);
        int o = rp[li] + slot;
        if (o < COLCAP) cols[o] = p[0];
    }
    __syncthreads();
    // contiguous col write (real count only)
    int nreal = bctl[b * 16 + 1]; if (nreal > COLCAP) nreal = COLCAP;
    for (int i = t; i < nreal; i += 256)
        col[base + i] = cols[i];
}

// ---------------- fused modality encoders + GCN layer-0 matmul ----------------
__global__ void __launch_bounds__(256) encmm0_kernel(
    const float* __restrict__ xf, const float* __restrict__ xw, const float* __restrict__ xt,
    const float* __restrict__ Wf, const float* __restrict__ bf,
    const float* __restrict__ Ww, const float* __restrict__ bw,
    const float* __restrict__ Wt, const float* __restrict__ bt,
    const float* __restrict__ W0, const float* __restrict__ dinv,
    float* __restrict__ h) {
    __shared__ float xin[64][32];    // fire[0..7], wea[8..19], ter[20..29]
    __shared__ float wenc[30][64];   // encoder weights (rows match xin cols)
    __shared__ float bs[192];        // encoder biases
    __shared__ float xs[64][36];     // encoder outputs for current 32-slice (+4 pad)
    __shared__ float ws[32][64];     // W0 rows for current slice
    int t = threadIdx.x;
    int n0 = blockIdx.x * 64;

    {   // stage raw inputs
        const float4* xf4 = (const float4*)xf;
        for (int i = t; i < 128; i += 256) {
            int n = i >> 1, q = i & 1;
            int gn = n0 + n;
            float4 v = make_float4(0, 0, 0, 0);
            if (gn < NN) v = xf4[(size_t)gn * 2 + q];
            *(float4*)&xin[n][q * 4] = v;
        }
        const float4* xw4 = (const float4*)xw;
        for (int i = t; i < 192; i += 256) {
            int n = i / 3, q = i - n * 3;
            int gn = n0 + n;
            float4 v = make_float4(0, 0, 0, 0);
            if (gn < NN) v = xw4[(size_t)gn * 3 + q];
            *(float4*)&xin[n][8 + q * 4] = v;
        }
        const float2* xt2 = (const float2*)xt;
        for (int i = t; i < 320; i += 256) {
            int n = i / 5, q = i - n * 5;
            int gn = n0 + n;
            float2 v = make_float2(0, 0);
            if (gn < NN) v = xt2[(size_t)gn * 5 + q];
            *(float2*)&xin[n][20 + q * 2] = v;
        }
        // stage encoder weights: rows 0-7 Wf, 8-19 Ww, 20-29 Wt
        for (int i = t; i < 480; i += 256) {
            int r = i >> 4, q = i & 15;
            float4 v;
            if (r < 8)       v = ((const float4*)Wf)[r * 16 + q];
            else if (r < 20) v = ((const float4*)Ww)[(r - 8) * 16 + q];
            else             v = ((const float4*)Wt)[(r - 20) * 16 + q];
            *(float4*)&wenc[r][q * 4] = v;
        }
        // stage encoder biases
        if (t < 192) bs[t] = (t < 64) ? bf[t] : (t < 128) ? bw[t - 64] : bt[t - 128];
    }

    int cg = t & 15, ng = t >> 4;
    int c0 = cg * 4;
    float4 acc[4];
    #pragma unroll
    for (int i = 0; i < 4; i++) acc[i] = make_float4(0, 0, 0, 0);

    for (int kq = 0; kq < 6; kq++) {
        __syncthreads();
        {   // stage W0 slice rows [kq*32, kq*32+32)
            const float4* W04 = (const float4*)W0;
            float4* ws4 = (float4*)&ws[0][0];
            for (int i = t; i < 512; i += 256)
                ws4[i] = W04[(size_t)kq * 512 + i];
        }
        // compute encoder outputs for this slice (uniform modality per kq)
        int coff = (kq < 2) ? kq * 32 : (kq < 4) ? (kq - 2) * 32 : (kq - 4) * 32;
        if (kq < 2) {
            for (int i = t; i < 2048; i += 256) {
                int n = i >> 5, kk = i & 31;
                float a = bs[kq * 32 + kk];
                #pragma unroll
                for (int k = 0; k < 8; k++) a = fmaf(xin[n][k], wenc[k][coff + kk], a);
                xs[n][kk] = fmaxf(a, 0.f);
            }
        } else if (kq < 4) {
            for (int i = t; i < 2048; i += 256) {
                int n = i >> 5, kk = i & 31;
                float a = bs[kq * 32 + kk];
                #pragma unroll
                for (int k = 0; k < 12; k++) a = fmaf(xin[n][8 + k], wenc[8 + k][coff + kk], a);
                xs[n][kk] = fmaxf(a, 0.f);
            }
        } else {
            for (int i = t; i < 2048; i += 256) {
                int n = i >> 5, kk = i & 31;
                float a = bs[kq * 32 + kk];
                #pragma unroll
                for (int k = 0; k < 10; k++) a = fmaf(xin[n][20 + k], wenc[20 + k][coff + kk], a);
                xs[n][kk] = fmaxf(a, 0.f);
            }
        }
        __syncthreads();
        // register-blocked fma over this 32-slice
        for (int k = 0; k < 32; k += 4) {
            float4 b0 = *(const float4*)&ws[k + 0][c0];
            float4 b1 = *(const float4*)&ws[k + 1][c0];
            float4 b2 = *(const float4*)&ws[k + 2][c0];
            float4 b3 = *(const float4*)&ws[k + 3][c0];
            #pragma unroll
            for (int i = 0; i < 4; i++) {
                float4 a = *(const float4*)&xs[ng * 4 + i][k];
                fma4(acc[i], a.x, b0); fma4(acc[i], a.y, b1);
                fma4(acc[i], a.z, b2); fma4(acc[i], a.w, b3);
            }
        }
    }
    float4* h4 = (float4*)h;
    #pragma unroll
    for (int i = 0; i < 4; i++) {
        int gn = n0 + ng * 4 + i;
        if (gn < NN) {
            float dn = dinv[gn];
            float4 v = acc[i];
            v.x *= dn; v.y *= dn; v.z *= dn; v.w *= dn;
            h4[(size_t)gn * 16 + cg] = v;
        }
    }
}

// ---------------- fused CSR gather + finalize + next-layer 64x64 matmul ----------------
// Grid-stride persistent blocks: W staged ONCE per block (was: once per 4 nodes
// = 256 staging loads/node, which starved the gather's memory parallelism).
// hout stored non-temporally so the 25.6 MB write-allocate doesn't evict the
// gather's h lines from L2.
__global__ void __launch_bounds__(256) gather_mm_kernel(
    const int* __restrict__ col, const int* __restrict__ rowptr,
    const float* __restrict__ dinv, const float* __restrict__ h,
    const float* __restrict__ bias, const float* __restrict__ W,
    float* __restrict__ hout) {
    __shared__ float Wl[64][64];
    int t = threadIdx.x;
    {
        const float4* W4 = (const float4*)W;
        float4* wl4 = (float4*)&Wl[0][0];
        for (int i = t; i < 1024; i += 256) wl4[i] = W4[i];
    }
    __syncthreads();
    int l = t & 63;
    int g = l >> 4;      // edge sub-slot 0..3
    int q = l & 15;      // float4 slot 0..15
    const float4* h4 = (const float4*)h;
    int wid = (blockIdx.x * 256 + t) >> 6;      // global wave id
    const int nwave = (GB * 256) >> 6;          // 8192 waves
    for (int n = wid; n < NN; n += nwave) {
        float4 acc = make_float4(0, 0, 0, 0);
        int r0 = rowptr[n], r1 = rowptr[n + 1];
        for (int base = r0; base < r1; base += 64) {
            int cnt = min(64, r1 - base);
            int pv = NN;                          // sentinel: zero row
            if (l < cnt) pv = __builtin_nontemporal_load(col + base + l);
            int steps = (cnt + 3) >> 2;
            int j = 0;
            for (; j + 4 <= steps; j += 4) {
                int e0 = (j + 0) * 4 + g, e1 = (j + 1) * 4 + g;
                int e2 = (j + 2) * 4 + g, e3 = (j + 3) * 4 + g;
                int s0 = __shfl(pv, e0);
                int s1 = __shfl(pv, e1);
                int s2 = __shfl(pv, e2);
                int s3 = __shfl(pv, e3);
                float4 v0 = h4[(size_t)s0 * 16 + q];
                float4 v1 = h4[(size_t)s1 * 16 + q];
                float4 v2 = h4[(size_t)s2 * 16 + q];
                float4 v3 = h4[(size_t)s3 * 16 + q];
                add4(acc, v0); add4(acc, v1);
                add4(acc, v2); add4(acc, v3);
            }
            for (; j < steps; j++) {
                int e = j * 4 + g;
                int s = __shfl(pv, e);
                float4 v = h4[(size_t)s * 16 + q];
                add4(acc, v);
            }
        }
        acc.x += __shfl_xor(acc.x, 16); acc.y += __shfl_xor(acc.y, 16);
        acc.z += __shfl_xor(acc.z, 16); acc.w += __shfl_xor(acc.w, 16);
        acc.x += __shfl_xor(acc.x, 32); acc.y += __shfl_xor(acc.y, 32);
        acc.z += __shfl_xor(acc.z, 32); acc.w += __shfl_xor(acc.w, 32);
        // layer output r (all lanes; q-slot replicated)
        float dn = dinv[n];
        float4 hn = h4[(size_t)n * 16 + q];   // hs[n] = h[n]*dinv[n]
        float4 b4 = ((const float4*)bias)[q];
        float4 r;
        r.x = fmaxf(fmaf(dn, acc.x + hn.x, b4.x), 0.f);
        r.y = fmaxf(fmaf(dn, acc.y + hn.y, b4.y), 0.f);
        r.z = fmaxf(fmaf(dn, acc.z + hn.z, b4.z), 0.f);
        r.w = fmaxf(fmaf(dn, acc.w + hn.w, b4.w), 0.f);
        // next-layer matmul: lane l computes output column l
        float oc = 0.f;
        #pragma unroll
        for (int qq = 0; qq < 16; qq++) {
            float rx = __shfl(r.x, qq);
            float ry = __shfl(r.y, qq);
            float rz = __shfl(r.z, qq);
            float rw = __shfl(r.w, qq);
            oc = fmaf(rx, Wl[qq * 4 + 0][l], oc);
            oc = fmaf(ry, Wl[qq * 4 + 1][l], oc);
            oc = fmaf(rz, Wl[qq * 4 + 2][l], oc);
            oc = fmaf(rw, Wl[qq * 4 + 3][l], oc);
        }
        __builtin_nontemporal_store(oc * dn, &hout[(size_t)n * 64 + l]);
    }
}

// ---------------- fused CSR gather + finalize + output MLP ----------------
__global__ void __launch_bounds__(256) gather_mlp_kernel(
    const int* __restrict__ col, const int* __restrict__ rowptr,
    const float* __restrict__ dinv, const float* __restrict__ h,
    const float* __restrict__ bias, const float* __restrict__ w1,
    const float* __restrict__ b1, const float* __restrict__ w2,
    const float* __restrict__ b2, float* __restrict__ out) {
    __shared__ float W1l[64][32];   // lane c reads W1l[k][c]: distinct banks
    __shared__ float w2l[32];
    __shared__ float b1l[32];
    int t = threadIdx.x;
    {
        const float4* w14 = (const float4*)w1;
        float4* wl4 = (float4*)&W1l[0][0];
        for (int i = t; i < 512; i += 256) wl4[i] = w14[i];
        if (t < 32) { w2l[t] = w2[t]; b1l[t] = b1[t]; }
    }
    __syncthreads();
    int l = t & 63;
    int g = l >> 4;
    int q = l & 15;
    const float4* h4 = (const float4*)h;
    int wid = (blockIdx.x * 256 + t) >> 6;
    const int nwave = (GB * 256) >> 6;
    for (int n = wid; n < NN; n += nwave) {
        float4 acc = make_float4(0, 0, 0, 0);
        int r0 = rowptr[n], r1 = rowptr[n + 1];
        for (int base = r0; base < r1; base += 64) {
            int cnt = min(64, r1 - base);
            int pv = NN;
            if (l < cnt) pv = __builtin_nontemporal_load(col + base + l);
            int steps = (cnt + 3) >> 2;
            int j = 0;
            for (; j + 4 <= steps; j += 4) {
                int e0 = (j + 0) * 4 + g, e1 = (j + 1) * 4 + g;
                int e2 = (j + 2) * 4 + g, e3 = (j + 3) * 4 + g;
                int s0 = __shfl(pv, e0);
                int s1 = __shfl(pv, e1);
                int s2 = __shfl(pv, e2);
                int s3 = __shfl(pv, e3);
                float4 v0 = h4[(size_t)s0 * 16 + q];
                float4 v1 = h4[(size_t)s1 * 16 + q];
                float4 v2 = h4[(size_t)s2 * 16 + q];
                float4 v3 = h4[(size_t)s3 * 16 + q];
                add4(acc, v0); add4(acc, v1);
                add4(acc, v2); add4(acc, v3);
            }
            for (; j < steps; j++) {
                int e = j * 4 + g;
                int s = __shfl(pv, e);
                float4 v = h4[(size_t)s * 16 + q];
                add4(acc, v);
            }
        }
        acc.x += __shfl_xor(acc.x, 16); acc.y += __shfl_xor(acc.y, 16);
        acc.z += __shfl_xor(acc.z, 16); acc.w += __shfl_xor(acc.w, 16);
        acc.x += __shfl_xor(acc.x, 32); acc.y += __shfl_xor(acc.y, 32);
        acc.z += __shfl_xor(acc.z, 32); acc.w += __shfl_xor(acc.w, 32);
        float dn = dinv[n];
        float4 hn = h4[(size_t)n * 16 + q];
        float4 b4 = ((const float4*)bias)[q];
        float4 r;
        r.x = fmaxf(fmaf(dn, acc.x + hn.x, b4.x), 0.f);
        r.y = fmaxf(fmaf(dn, acc.y + hn.y, b4.y), 0.f);
        r.z = fmaxf(fmaf(dn, acc.z + hn.z, b4.z), 0.f);
        r.w = fmaxf(fmaf(dn, acc.w + hn.w, b4.w), 0.f);
        // output MLP: hidden unit c = l&31
        int c = l & 31;
        float a2 = b1l[c];
        #pragma unroll
        for (int qq = 0; qq < 16; qq++) {
            float rx = __shfl(r.x, qq);
            float ry = __shfl(r.y, qq);
            float rz = __shfl(r.z, qq);
            float rw = __shfl(r.w, qq);
            a2 = fmaf(rx, W1l[qq * 4 + 0][c], a2);
            a2 = fmaf(ry, W1l[qq * 4 + 1][c], a2);
            a2 = fmaf(rz, W1l[qq * 4 + 2][c], a2);
            a2 = fmaf(rw, W1l[qq * 4 + 3][c], a2);
        }
        float v = fmaxf(a2, 0.f) * w2l[c];
        v += __shfl_xor(v, 1); v += __shfl_xor(v, 2);
        v += __shfl_xor(v, 4); v += __shfl_xor(v, 8);
        v += __shfl_xor(v, 16);
        if (l == 0) __builtin_nontemporal_store(v + b2[0], &out[n]);
    }
}

extern "C" void kernel_launch(void* const* d_in, const int* in_sizes, int n_in,
                              void* d_out, int out_size, void* d_ws, size_t ws_size,
                              hipStream_t stream) {
    const float* xf = (const float*)d_in[0];
    const float* xw = (const float*)d_in[1];
    const float* xt = (const float*)d_in[2];
    const int*   ei = (const int*)d_in[3];
    const int*   src = ei;
    const int*   dst = ei + NE;
    const float* Wf = (const float*)d_in[4];
    const float* bf = (const float*)d_in[5];
    const float* Ww = (const float*)d_in[6];
    const float* bw = (const float*)d_in[7];
    const float* Wt = (const float*)d_in[8];
    const float* bt = (const float*)d_in[9];
    const float* W0 = (const float*)d_in[10];
    const float* b0 = (const float*)d_in[11];
    const float* W1 = (const float*)d_in[12];
    const float* b1 = (const float*)d_in[13];
    const float* W2 = (const float*)d_in[14];
    const float* b2 = (const float*)d_in[15];
    const float* ow1 = (const float*)d_in[16];
    const float* ob1 = (const float*)d_in[17];
    const float* ow2 = (const float*)d_in[18];
    const float* ob2 = (const float*)d_in[19];
    float* out = (float*)d_out;

    // workspace layout. pairs (42 MB) ALIASES hA+hB: dead before encmm0 writes hA.
    char* w = (char*)d_ws;
    float* hA     = (float*)w;  w += (size_t)(NN + 1) * 64 * 4;      // 25.6 MB (+zero row)
    float* hB     = (float*)w;  w += (size_t)(NN + 1) * 64 * 4;      // 25.6 MB (+zero row)
    int*   col    = (int*)w;    w += (size_t)NE * 4;                 // 12.8 MB
    v2i*   povf   = (v2i*)w;    w += (size_t)NBUCK * OVFCAP * 8;     // 1 MB
    float* dinv   = (float*)w;  w += (size_t)NN * 4;
    int*   rowptr = (int*)w;    w += (size_t)(NN + 1) * 4;
    int*   bctl   = (int*)w;    w += (size_t)NBUCK * 16 * 4;         // 16 KB (padded lines)
    int*   bbase  = (int*)w;    w += (size_t)NBUCK * 4;
    v2i*   pairs  = (v2i*)hA;                                        // alias (42 MB <= 51.2 MB)

    // ---- CSR build (two-phase, line-staged; reused by all 3 layers) ----
    hipMemsetAsync(bctl, 0, (size_t)NBUCK * 16 * 4, stream);
    partition_kernel<<<P1_GRID, 256, 0, stream>>>(src, dst, bctl, pairs, povf);
    bucket_scan_kernel<<<1, NBUCK, 0, stream>>>(bctl, bbase, rowptr);
    csr_fill_kernel<<<NBUCK, 256, 0, stream>>>(pairs, povf, bctl, bbase, rowptr, dinv, col);
    // sentinel zero rows (after pairs is dead)
    hipMemsetAsync(hA + (size_t)NN * 64, 0, 64 * 4, stream);
    hipMemsetAsync(hB + (size_t)NN * 64, 0, 64 * 4, stream);

    // ---- layer 0: fused encoders + matmul (scaled) -> hA ----
    encmm0_kernel<<<(NN + 63) / 64, 256, 0, stream>>>(xf, xw, xt, Wf, bf, Ww, bw, Wt, bt, W0, dinv, hA);
    // ---- gather(b0) + mm(W1) : hA -> hB ----
    gather_mm_kernel<<<GB, 256, 0, stream>>>(col, rowptr, dinv, hA, b0, W1, hB);
    // ---- gather(b1) + mm(W2) : hB -> hA ----
    gather_mm_kernel<<<GB, 256, 0, stream>>>(col, rowptr, dinv, hB, b1, W2, hA);
    // ---- gather(b2) + output MLP : hA -> out ----
    gather_mlp_kernel<<<GB, 256, 0, stream>>>(col, rowptr, dinv, hA, b2, ow1, ob1, ow2, ob2, out);
}